// Round 18
// baseline (200.428 us; speedup 1.0000x reference)
//
#include <hip/hip_runtime.h>

using f32x4  = __attribute__((ext_vector_type(4))) float;
using bf16x4 = __attribute__((ext_vector_type(4))) __bf16;
using bf16x8 = __attribute__((ext_vector_type(8))) __bf16;

#define L_SEQ 1024
#define D_MODEL 1536
#define D_INNER 3072
#define DT_RANK 96
#define D_STATE 16

#define SCAN_NC 32          // chunks over L
#define SCAN_CL (L_SEQ / SCAN_NC)     // 32
#define NCHAIN  (D_INNER * D_STATE)   // 49152 (d,n) chains

// Static fallback scratch (layout now: 5 bf16 [L][D] bufs + dbl + 3 chain bufs
// ~51 MB; keep the old larger size for safety).
#define SCRATCH_FLOATS (4 * L_SEQ * D_INNER + L_SEQ * 128 + 3 * SCAN_NC * NCHAIN)
__device__ __align__(16) float g_scratch[SCRATCH_FLOATS];

template <bool B16> struct RegT { using T = f32x4; };
template <> struct RegT<true> { using T = uint4; };

// ---------------------------------------------------------------------------
// BT GEMM: C[M][N] = sum_k A[M][K] * B[N][K]  (B N-major).
// 1-deep register prefetch + row-contiguous lane mapping; compute() iterates
// BK/32 MFMA sub-steps per staged tile. 128x64 (K1) / 64x64 tiles proven.
// AMODE/BMODE: 0 = input already bf16 (16B LDS copies, no cvt);
//              1 = f32 -> bf16; 2 = f32 -> (hi,lo) bf16 (per-side hi/lo:
//              A2B2=3 MFMAs, A2B1=2, A0/1·B2=2, else 1).
// EPI: 0 = split bf16 stores (x|z); 1 = softplus(acc+bias[col]) bf16;
//      2 = atomicAdd f32 (split-K, target pre-zeroed).
// SWZY>0: 1-D grid 8*SWZY*(M/BM), XCD-chunked N (bijective).
// ---------------------------------------------------------------------------
template <int BM, int BN, int BK, int AMODE, int BMODE, int EPI, int SWZY = 0>
__global__ __launch_bounds__(256) void gemm_bt(
    const void* __restrict__ Ap, const void* __restrict__ Bp,
    void* __restrict__ out0, void* __restrict__ out1,
    const float* __restrict__ bias,
    int M, int N, int K, int lda, int ldb, int ldc)
{
    constexpr int LDSK = BK + 8;
    constexpr int WM = BM / 2, WN = BN / 2;
    constexpr int FM = WM / 16, FN = WN / 16;
    constexpr int AEPT = (AMODE == 0) ? 8 : 4;
    constexpr int BEPT = (BMODE == 0) ? 8 : 4;
    constexpr int CHA = (BM * BK / 256) / AEPT;
    constexpr int CHB = (BN * BK / 256) / BEPT;
    constexpr int ACPR = BK / AEPT, BCPR = BK / BEPT;
    using ART = typename RegT<AMODE == 0>::T;
    using BRT = typename RegT<BMODE == 0>::T;
    __shared__ __align__(16) __bf16 As [BM * LDSK];
    __shared__ __align__(16) __bf16 As2[(AMODE == 2) ? BM * LDSK : 8];
    __shared__ __align__(16) __bf16 Bs [BN * LDSK];
    __shared__ __align__(16) __bf16 Bs2[(BMODE == 2) ? BN * LDSK : 8];

    const int tid  = threadIdx.x;
    const int lane = tid & 63;
    const int wid  = tid >> 6;
    const int wm = wid >> 1, wn = wid & 1;

    int m0, n0;
    if constexpr (SWZY > 0) {
        int b   = blockIdx.x;
        int xcd = b & 7;
        int j   = b >> 3;
        m0 = (j / SWZY) * BM;
        n0 = (xcd * SWZY + (j % SWZY)) * BN;
    } else {
        m0 = blockIdx.x * BM;
        n0 = blockIdx.y * BN;
    }

    const int nkt = (K + BK - 1) / BK;
    const int per = (nkt + (int)gridDim.z - 1) / (int)gridDim.z;
    const int kb  = blockIdx.z * per * BK;
    const int ke  = min(K, kb + per * BK);

    f32x4 acc[FM][FN];
#pragma unroll
    for (int i = 0; i < FM; ++i)
#pragma unroll
        for (int j = 0; j < FN; ++j) acc[i][j] = f32x4{0.f, 0.f, 0.f, 0.f};

    const int fr = lane & 15, kq = lane >> 4;

    ART arg[CHA];
    BRT brg[CHB];

    auto loadA = [&](int kt) {
#pragma unroll
        for (int i = 0; i < CHA; ++i) {
            int c = i * 256 + tid;
            int r = c / ACPR, k = c % ACPR;
            if constexpr (AMODE == 0) {
                const __bf16* A = (const __bf16*)Ap;
                arg[i] = *(const uint4*)(A + (size_t)(m0 + r) * lda + kt + k * 8);
            } else {
                const float* A = (const float*)Ap;
                arg[i] = *(const f32x4*)(A + (size_t)(m0 + r) * lda + kt + k * 4);
            }
        }
    };
    auto loadB = [&](int kt) {
#pragma unroll
        for (int i = 0; i < CHB; ++i) {
            int c = i * 256 + tid;
            int r = c / BCPR, k = c % BCPR;
            if constexpr (BMODE == 0) {
                const __bf16* B = (const __bf16*)Bp;
                brg[i] = *(const uint4*)(B + (size_t)(n0 + r) * ldb + kt + k * 8);
            } else {
                const float* B = (const float*)Bp;
                brg[i] = *(const f32x4*)(B + (size_t)(n0 + r) * ldb + kt + k * 4);
            }
        }
    };
    auto writeA = [&]() {
#pragma unroll
        for (int i = 0; i < CHA; ++i) {
            int c = i * 256 + tid;
            int r = c / ACPR, k = c % ACPR;
            if constexpr (AMODE == 0) {
                *(uint4*)&As[r * LDSK + k * 8] = arg[i];
            } else {
                bf16x4 hv;
#pragma unroll
                for (int e = 0; e < 4; ++e) hv[e] = (__bf16)arg[i][e];
                *(bf16x4*)&As[r * LDSK + k * 4] = hv;
                if constexpr (AMODE == 2) {
                    bf16x4 lv;
#pragma unroll
                    for (int e = 0; e < 4; ++e)
                        lv[e] = (__bf16)(arg[i][e] - (float)hv[e]);
                    *(bf16x4*)&As2[r * LDSK + k * 4] = lv;
                }
            }
        }
    };
    auto writeB = [&]() {
#pragma unroll
        for (int i = 0; i < CHB; ++i) {
            int c = i * 256 + tid;
            int r = c / BCPR, k = c % BCPR;
            if constexpr (BMODE == 0) {
                *(uint4*)&Bs[r * LDSK + k * 8] = brg[i];
            } else {
                bf16x4 hv;
#pragma unroll
                for (int e = 0; e < 4; ++e) hv[e] = (__bf16)brg[i][e];
                *(bf16x4*)&Bs[r * LDSK + k * 4] = hv;
                if constexpr (BMODE == 2) {
                    bf16x4 lv;
#pragma unroll
                    for (int e = 0; e < 4; ++e)
                        lv[e] = (__bf16)(brg[i][e] - (float)hv[e]);
                    *(bf16x4*)&Bs2[r * LDSK + k * 4] = lv;
                }
            }
        }
    };
    auto compute = [&]() {
#pragma unroll
        for (int ks = 0; ks < BK / 32; ++ks) {
            const int kc = ks * 32 + kq * 8;
            bf16x8 af[FM], bfg[FN];
#pragma unroll
            for (int fm = 0; fm < FM; ++fm)
                af[fm] = *(const bf16x8*)&As[(wm * WM + fm * 16 + fr) * LDSK + kc];
#pragma unroll
            for (int fn = 0; fn < FN; ++fn)
                bfg[fn] = *(const bf16x8*)&Bs[(wn * WN + fn * 16 + fr) * LDSK + kc];
            if constexpr (AMODE == 2 && BMODE == 2) {
                bf16x8 al[FM], bl[FN];
#pragma unroll
                for (int fm = 0; fm < FM; ++fm)
                    al[fm] = *(const bf16x8*)&As2[(wm * WM + fm * 16 + fr) * LDSK + kc];
#pragma unroll
                for (int fn = 0; fn < FN; ++fn)
                    bl[fn] = *(const bf16x8*)&Bs2[(wn * WN + fn * 16 + fr) * LDSK + kc];
#pragma unroll
                for (int fm = 0; fm < FM; ++fm)
#pragma unroll
                    for (int fn = 0; fn < FN; ++fn) {
                        acc[fm][fn] = __builtin_amdgcn_mfma_f32_16x16x32_bf16(
                            al[fm], bfg[fn], acc[fm][fn], 0, 0, 0);
                        acc[fm][fn] = __builtin_amdgcn_mfma_f32_16x16x32_bf16(
                            af[fm], bl[fn], acc[fm][fn], 0, 0, 0);
                        acc[fm][fn] = __builtin_amdgcn_mfma_f32_16x16x32_bf16(
                            af[fm], bfg[fn], acc[fm][fn], 0, 0, 0);
                    }
            } else if constexpr (AMODE == 2) {
                bf16x8 al[FM];
#pragma unroll
                for (int fm = 0; fm < FM; ++fm)
                    al[fm] = *(const bf16x8*)&As2[(wm * WM + fm * 16 + fr) * LDSK + kc];
#pragma unroll
                for (int fm = 0; fm < FM; ++fm)
#pragma unroll
                    for (int fn = 0; fn < FN; ++fn) {
                        acc[fm][fn] = __builtin_amdgcn_mfma_f32_16x16x32_bf16(
                            al[fm], bfg[fn], acc[fm][fn], 0, 0, 0);
                        acc[fm][fn] = __builtin_amdgcn_mfma_f32_16x16x32_bf16(
                            af[fm], bfg[fn], acc[fm][fn], 0, 0, 0);
                    }
            } else if constexpr (BMODE == 2) {
                bf16x8 bl[FN];
#pragma unroll
                for (int fn = 0; fn < FN; ++fn)
                    bl[fn] = *(const bf16x8*)&Bs2[(wn * WN + fn * 16 + fr) * LDSK + kc];
#pragma unroll
                for (int fm = 0; fm < FM; ++fm)
#pragma unroll
                    for (int fn = 0; fn < FN; ++fn) {
                        acc[fm][fn] = __builtin_amdgcn_mfma_f32_16x16x32_bf16(
                            af[fm], bl[fn], acc[fm][fn], 0, 0, 0);
                        acc[fm][fn] = __builtin_amdgcn_mfma_f32_16x16x32_bf16(
                            af[fm], bfg[fn], acc[fm][fn], 0, 0, 0);
                    }
            } else {
#pragma unroll
                for (int fm = 0; fm < FM; ++fm)
#pragma unroll
                    for (int fn = 0; fn < FN; ++fn)
                        acc[fm][fn] = __builtin_amdgcn_mfma_f32_16x16x32_bf16(
                            af[fm], bfg[fn], acc[fm][fn], 0, 0, 0);
            }
        }
    };

    loadA(kb);
    loadB(kb);

    for (int kt = kb; kt < ke; kt += BK) {
        writeA();
        writeB();
        __syncthreads();
        if (kt + BK < ke) {
            loadA(kt + BK);
            loadB(kt + BK);
        }
        compute();
        __syncthreads();
    }

    const int rbase = m0 + wm * WM, cbase = n0 + wn * WN;
#pragma unroll
    for (int fm = 0; fm < FM; ++fm) {
#pragma unroll
        for (int fn = 0; fn < FN; ++fn) {
            int row = rbase + fm * 16 + (lane >> 4) * 4;
            int col = cbase + fn * 16 + (lane & 15);
            f32x4 v = acc[fm][fn];
            if (EPI == 0) {
                int split = N / 2;
                __bf16* d = (col < split) ? (__bf16*)out0 : (__bf16*)out1;
                int cc = (col < split) ? col : col - split;
#pragma unroll
                for (int j = 0; j < 4; ++j)
                    d[(size_t)(row + j) * ldc + cc] = (__bf16)v[j];
            } else if (EPI == 1) {
                float bz = bias[col];
                __bf16* d = (__bf16*)out0;
#pragma unroll
                for (int j = 0; j < 4; ++j) {
                    float t = v[j] + bz;
                    t = (t > 20.f) ? t : log1pf(__expf(t));
                    d[(size_t)(row + j) * ldc + col] = (__bf16)t;
                }
            } else {   // EPI == 2: atomicAdd f32 (target pre-zeroed)
                float* d = (float*)out0;
#pragma unroll
                for (int j = 0; j < 4; ++j)
                    atomicAdd(&d[(size_t)(row + j) * ldc + col], v[j]);
            }
        }
    }
}

// ---------------------------------------------------------------------------
__global__ __launch_bounds__(256) void zero_f32(float* __restrict__ p, int n4)
{
    int i = blockIdx.x * 256 + threadIdx.x;
    if (i < n4) ((f32x4*)p)[i] = f32x4{0.f, 0.f, 0.f, 0.f};
}

// ---------------------------------------------------------------------------
// Depthwise conv (width 4, left-pad 3) + SiLU.  x, xc: [L][D_INNER] bf16.
// conv_state[d][j] = x[1020+j][d] (f32, from bf16 x). Also zeroes dbl.
// ---------------------------------------------------------------------------
__global__ __launch_bounds__(256) void conv_silu(
    const __bf16* __restrict__ x, const float* __restrict__ cw,
    const float* __restrict__ cb, __bf16* __restrict__ xc,
    float* __restrict__ conv_state, float* __restrict__ dbl)
{
    int idx = blockIdx.x * 256 + threadIdx.x;
    if (idx < L_SEQ * 128 / 4)
        ((f32x4*)dbl)[idx] = f32x4{0.f, 0.f, 0.f, 0.f};
    int l  = idx / (D_INNER / 4);
    int d4 = (idx % (D_INNER / 4)) * 4;
    const bf16x4 bz = bf16x4{(__bf16)0.f, (__bf16)0.f, (__bf16)0.f, (__bf16)0.f};
    bf16x4 u0 = *(const bf16x4*)&x[(size_t)l * D_INNER + d4];
    bf16x4 u1 = (l >= 1) ? *(const bf16x4*)&x[(size_t)(l - 1) * D_INNER + d4] : bz;
    bf16x4 u2 = (l >= 2) ? *(const bf16x4*)&x[(size_t)(l - 2) * D_INNER + d4] : bz;
    bf16x4 u3 = (l >= 3) ? *(const bf16x4*)&x[(size_t)(l - 3) * D_INNER + d4] : bz;
    bf16x4 r;
#pragma unroll
    for (int i = 0; i < 4; ++i) {
        int d = d4 + i;
        float w0 = cw[d * 4 + 0], w1 = cw[d * 4 + 1];
        float w2 = cw[d * 4 + 2], w3 = cw[d * 4 + 3];
        float v = cb[d] + w3 * (float)u0[i] + w2 * (float)u1[i]
                        + w1 * (float)u2[i] + w0 * (float)u3[i];
        r[i] = (__bf16)(v / (1.f + __expf(-v)));
    }
    *(bf16x4*)&xc[(size_t)l * D_INNER + d4] = r;
    if (l == L_SEQ - 1) {
#pragma unroll
        for (int i = 0; i < 4; ++i) {
            int d = d4 + i;
            conv_state[d * 4 + 3] = (float)u0[i];
            conv_state[d * 4 + 2] = (float)u1[i];
            conv_state[d * 4 + 1] = (float)u2[i];
            conv_state[d * 4 + 0] = (float)u3[i];
        }
    }
}

// ---------------------------------------------------------------------------
// Chunked scan, phase 1. Thread = d (lane-coalesced), block.y = chunk.
// delta, xc: [L][D] bf16.  All 16 n-states in registers.
// ---------------------------------------------------------------------------
__global__ __launch_bounds__(256) void scan_phase1(
    const __bf16* __restrict__ delta, const __bf16* __restrict__ xc,
    const float* __restrict__ dbl, const float* __restrict__ A_log,
    float* __restrict__ U, float* __restrict__ Aprod)
{
    int d = blockIdx.x * 256 + threadIdx.x;
    int c = blockIdx.y;
    float a[D_STATE], h[D_STATE], p[D_STATE];
#pragma unroll
    for (int n = 0; n < D_STATE; n += 4) {
        f32x4 av = *(const f32x4*)&A_log[d * D_STATE + n];
#pragma unroll
        for (int e = 0; e < 4; ++e) {
            a[n + e] = __expf(av[e]);
            h[n + e] = 0.f;
            p[n + e] = 1.f;
        }
    }
    int l0 = c * SCAN_CL;
    for (int i = 0; i < SCAN_CL; ++i) {
        int l = l0 + i;
        float dl = (float)delta[(size_t)l * D_INNER + d];
        float xv = (float)xc[(size_t)l * D_INNER + d];
        const float* Bp = dbl + l * 128 + DT_RANK;
        f32x4 B0 = *(const f32x4*)(Bp);
        f32x4 B1 = *(const f32x4*)(Bp + 4);
        f32x4 B2 = *(const f32x4*)(Bp + 8);
        f32x4 B3 = *(const f32x4*)(Bp + 12);
        float dx = dl * xv;
#pragma unroll
        for (int n = 0; n < D_STATE; ++n) {
            float Bv = (n < 4) ? B0[n] : (n < 8) ? B1[n - 4]
                     : (n < 12) ? B2[n - 8] : B3[n - 12];
            float dA = __expf(-dl * a[n]);
            h[n] = fmaf(dA, h[n], dx * Bv);
            p[n] *= dA;
        }
    }
    size_t base = (size_t)c * NCHAIN + (size_t)d * D_STATE;
#pragma unroll
    for (int n = 0; n < D_STATE; n += 4) {
        *(f32x4*)&U[base + n]     = f32x4{h[n], h[n+1], h[n+2], h[n+3]};
        *(f32x4*)&Aprod[base + n] = f32x4{p[n], p[n+1], p[n+2], p[n+3]};
    }
}

// ---------------------------------------------------------------------------
// Phase 2: per (d,n) serial combine over NC chunks; writes last_state (f32).
// ---------------------------------------------------------------------------
__global__ __launch_bounds__(256) void scan_phase2(
    const float* __restrict__ U, const float* __restrict__ Aprod,
    float* __restrict__ Hin, float* __restrict__ last_state)
{
    int r = blockIdx.x * 256 + threadIdx.x;
    float hin = 0.f;
#pragma unroll
    for (int c = 0; c < SCAN_NC; ++c) {
        Hin[c * NCHAIN + r] = hin;
        hin = fmaf(Aprod[c * NCHAIN + r], hin, U[c * NCHAIN + r]);
    }
    last_state[r] = hin;
}

// ---------------------------------------------------------------------------
// Phase 3: seeded local scan; y = (sum_n h*C + D*xc)*silu(z) -> bf16 [L][D].
// ---------------------------------------------------------------------------
__global__ __launch_bounds__(256) void scan_phase3(
    const __bf16* __restrict__ delta, const __bf16* __restrict__ xc,
    const __bf16* __restrict__ z, const float* __restrict__ dbl,
    const float* __restrict__ A_log, const float* __restrict__ Dp,
    const float* __restrict__ Hin, __bf16* __restrict__ y)
{
    int d = blockIdx.x * 256 + threadIdx.x;
    int c = blockIdx.y;
    float a[D_STATE], h[D_STATE];
    size_t hbase = (size_t)c * NCHAIN + (size_t)d * D_STATE;
#pragma unroll
    for (int n = 0; n < D_STATE; n += 4) {
        f32x4 av = *(const f32x4*)&A_log[d * D_STATE + n];
        f32x4 hv = *(const f32x4*)&Hin[hbase + n];
#pragma unroll
        for (int e = 0; e < 4; ++e) {
            a[n + e] = __expf(av[e]);
            h[n + e] = hv[e];
        }
    }
    float Dv = Dp[d];
    int l0 = c * SCAN_CL;
    for (int i = 0; i < SCAN_CL; ++i) {
        int l = l0 + i;
        float dl = (float)delta[(size_t)l * D_INNER + d];
        float xv = (float)xc[(size_t)l * D_INNER + d];
        float zv = (float)z[(size_t)l * D_INNER + d];
        const float* Bp = dbl + l * 128 + DT_RANK;
        f32x4 B0 = *(const f32x4*)(Bp);
        f32x4 B1 = *(const f32x4*)(Bp + 4);
        f32x4 B2 = *(const f32x4*)(Bp + 8);
        f32x4 B3 = *(const f32x4*)(Bp + 12);
        f32x4 C0 = *(const f32x4*)(Bp + 16);
        f32x4 C1 = *(const f32x4*)(Bp + 20);
        f32x4 C2 = *(const f32x4*)(Bp + 24);
        f32x4 C3 = *(const f32x4*)(Bp + 28);
        float dx = dl * xv;
        float yv = 0.f;
#pragma unroll
        for (int n = 0; n < D_STATE; ++n) {
            float Bv = (n < 4) ? B0[n] : (n < 8) ? B1[n - 4]
                     : (n < 12) ? B2[n - 8] : B3[n - 12];
            float Cv = (n < 4) ? C0[n] : (n < 8) ? C1[n - 4]
                     : (n < 12) ? C2[n - 8] : C3[n - 12];
            float dA = __expf(-dl * a[n]);
            h[n] = fmaf(dA, h[n], dx * Bv);
            yv = fmaf(h[n], Cv, yv);
        }
        float sz = zv / (1.f + __expf(-zv));
        y[(size_t)l * D_INNER + d] = (__bf16)((yv + Dv * xv) * sz);
    }
}

// ---------------------------------------------------------------------------
extern "C" void kernel_launch(void* const* d_in, const int* in_sizes, int n_in,
                              void* d_out, int out_size, void* d_ws, size_t ws_size,
                              hipStream_t stream)
{
    const float* hs    = (const float*)d_in[0];
    const float* Win   = (const float*)d_in[1];
    const float* cw    = (const float*)d_in[2];
    const float* cb    = (const float*)d_in[3];
    const float* Wx    = (const float*)d_in[4];
    const float* Wdt   = (const float*)d_in[5];
    const float* dtb   = (const float*)d_in[6];
    const float* Wout  = (const float*)d_in[7];
    const float* A_log = (const float*)d_in[8];
    const float* Dp    = (const float*)d_in[9];

    float* out        = (float*)d_out;
    float* conv_state = out + (size_t)L_SEQ * D_MODEL;
    float* last_state = conv_state + (size_t)D_INNER * 4;

    const size_t NEED = sizeof(float) * (size_t)SCRATCH_FLOATS;
    float* base;
    if (ws_size >= NEED) {
        base = (float*)d_ws;
    } else {
        void* sp = nullptr;
        hipGetSymbolAddress(&sp, HIP_SYMBOL(g_scratch));
        base = (float*)sp;
    }
    // bf16 intermediates: x, z, xc, delta, y = 5 x [L][D] bf16 (31.5 MB)
    __bf16* xB  = (__bf16*)base;
    __bf16* zB  = xB  + (size_t)L_SEQ * D_INNER;
    __bf16* xcB = zB  + (size_t)L_SEQ * D_INNER;
    __bf16* dlB = xcB + (size_t)L_SEQ * D_INNER;
    __bf16* yB  = dlB + (size_t)L_SEQ * D_INNER;
    float* dbl  = (float*)(yB + (size_t)L_SEQ * D_INNER);  // [1024][128]
    float* Ubuf = dbl  + (size_t)L_SEQ * 128;
    float* Abuf = Ubuf + (size_t)SCAN_NC * NCHAIN;
    float* Hbuf = Abuf + (size_t)SCAN_NC * NCHAIN;

    // K1: xz = hs @ Win^T -> x (bf16), z (bf16).
    // BK=64, BM128/BN64, SWZY=12, grid 768. (round-15/17 best geometry)
    gemm_bt<128, 64, 64, 1, 1, 0, 12><<<dim3(768), 256, 0, stream>>>(
        hs, Win, xB, zB, nullptr, L_SEQ, 2 * D_INNER, D_MODEL, D_MODEL, D_MODEL, D_INNER);

    // K2: conv + silu -> xc (bf16); conv_state (f32); zeroes dbl
    conv_silu<<<dim3(L_SEQ * D_INNER / 4 / 256), 256, 0, stream>>>(
        xB, cw, cb, xcB, conv_state, dbl);

    // K3: dbl = xc @ Wx^T (A bf16-direct, B hi/lo f32; split-K 24, atomic)
    gemm_bt<64, 128, 32, 0, 2, 2><<<dim3(16, 1, 24), 256, 0, stream>>>(
        xcB, Wx, dbl, nullptr, nullptr, L_SEQ, 128, D_INNER, D_INNER, D_INNER, 128);

    // K4: delta = softplus(dt @ Wdt^T + b) -> bf16. BK=96 single tile,
    // hi/lo both sides (dbl f32, Wdt f32).
    gemm_bt<64, 64, 96, 2, 2, 1><<<dim3(16, 48), 256, 0, stream>>>(
        dbl, Wdt, dlB, nullptr, dtb, L_SEQ, D_INNER, DT_RANK, 128, DT_RANK, D_INNER);

    // K5: chunked scan (3 phases) -> y (bf16), last_state
    scan_phase1<<<dim3(D_INNER / 256, SCAN_NC), 256, 0, stream>>>(
        dlB, xcB, dbl, A_log, Ubuf, Abuf);
    scan_phase2<<<dim3(NCHAIN / 256), 256, 0, stream>>>(
        Ubuf, Abuf, Hbuf, last_state);
    scan_phase3<<<dim3(D_INNER / 256, SCAN_NC), 256, 0, stream>>>(
        dlB, xcB, zB, dbl, A_log, Dp, Hbuf, yB);

    // K7: out = y @ Wout^T (A bf16-direct), split-K=2 atomicAdd into
    // pre-zeroed out (2 contributions: IEEE-commutative, deterministic).
    zero_f32<<<dim3(L_SEQ * D_MODEL / 4 / 256), 256, 0, stream>>>(
        out, L_SEQ * D_MODEL / 4);
    gemm_bt<64, 64, 64, 0, 1, 2><<<dim3(16, 24, 2), 256, 0, stream>>>(
        yB, Wout, out, nullptr, nullptr, L_SEQ, D_MODEL, D_INNER, D_INNER, D_INNER, D_MODEL);
}

// Round 19
// 199.443 us; speedup vs baseline: 1.0049x; 1.0049x over previous
//
#include <hip/hip_runtime.h>

using f32x4  = __attribute__((ext_vector_type(4))) float;
using bf16x4 = __attribute__((ext_vector_type(4))) __bf16;
using bf16x8 = __attribute__((ext_vector_type(8))) __bf16;

#define L_SEQ 1024
#define D_MODEL 1536
#define D_INNER 3072
#define DT_RANK 96
#define D_STATE 16

#define SCAN_NC 32          // chunks over L
#define SCAN_CL (L_SEQ / SCAN_NC)     // 32
#define NCHAIN  (D_INNER * D_STATE)   // 49152 (d,n) chains

// Static fallback scratch: 5 bf16 [L][D] + dbl + 3 chain bufs + K7 slab.
#define SCRATCH_FLOATS (4 * L_SEQ * D_INNER + L_SEQ * 128 + 3 * SCAN_NC * NCHAIN)
__device__ __align__(16) float g_scratch[SCRATCH_FLOATS];

template <bool B16> struct RegT { using T = f32x4; };
template <> struct RegT<true> { using T = uint4; };

// ---------------------------------------------------------------------------
// BT GEMM: C[M][N] = sum_k A[M][K] * B[N][K]  (B N-major).
// 1-deep register prefetch + row-contiguous lane mapping; compute() iterates
// BK/32 MFMA sub-steps per staged tile.
// AMODE/BMODE: 0 = input already bf16 (16B LDS copies, no cvt);
//              1 = f32 -> bf16; 2 = f32 -> (hi,lo) bf16 pair.
// EPI: 0 = split bf16 stores (x|z); 1 = softplus(acc+bias[col]) bf16;
//      2 = atomicAdd f32 (ONLY for small L2-resident targets — r18 lesson:
//          on streamed outputs atomics amplify traffic ~8x);
//      4 = split-K partial f32 slab (out0 + z*M*ldc), reduce separately.
// SWZY>0: 1-D grid 8*SWZY*(M/BM), XCD-chunked N (bijective).
// ---------------------------------------------------------------------------
template <int BM, int BN, int BK, int AMODE, int BMODE, int EPI, int SWZY = 0>
__global__ __launch_bounds__(256) void gemm_bt(
    const void* __restrict__ Ap, const void* __restrict__ Bp,
    void* __restrict__ out0, void* __restrict__ out1,
    const float* __restrict__ bias,
    int M, int N, int K, int lda, int ldb, int ldc)
{
    constexpr int LDSK = BK + 8;
    constexpr int WM = BM / 2, WN = BN / 2;
    constexpr int FM = WM / 16, FN = WN / 16;
    constexpr int AEPT = (AMODE == 0) ? 8 : 4;
    constexpr int BEPT = (BMODE == 0) ? 8 : 4;
    constexpr int CHA = (BM * BK / 256) / AEPT;
    constexpr int CHB = (BN * BK / 256) / BEPT;
    constexpr int ACPR = BK / AEPT, BCPR = BK / BEPT;
    using ART = typename RegT<AMODE == 0>::T;
    using BRT = typename RegT<BMODE == 0>::T;
    __shared__ __align__(16) __bf16 As [BM * LDSK];
    __shared__ __align__(16) __bf16 As2[(AMODE == 2) ? BM * LDSK : 8];
    __shared__ __align__(16) __bf16 Bs [BN * LDSK];
    __shared__ __align__(16) __bf16 Bs2[(BMODE == 2) ? BN * LDSK : 8];

    const int tid  = threadIdx.x;
    const int lane = tid & 63;
    const int wid  = tid >> 6;
    const int wm = wid >> 1, wn = wid & 1;

    int m0, n0;
    if constexpr (SWZY > 0) {
        int b   = blockIdx.x;
        int xcd = b & 7;
        int j   = b >> 3;
        m0 = (j / SWZY) * BM;
        n0 = (xcd * SWZY + (j % SWZY)) * BN;
    } else {
        m0 = blockIdx.x * BM;
        n0 = blockIdx.y * BN;
    }

    const int nkt = (K + BK - 1) / BK;
    const int per = (nkt + (int)gridDim.z - 1) / (int)gridDim.z;
    const int kb  = blockIdx.z * per * BK;
    const int ke  = min(K, kb + per * BK);

    f32x4 acc[FM][FN];
#pragma unroll
    for (int i = 0; i < FM; ++i)
#pragma unroll
        for (int j = 0; j < FN; ++j) acc[i][j] = f32x4{0.f, 0.f, 0.f, 0.f};

    const int fr = lane & 15, kq = lane >> 4;

    ART arg[CHA];
    BRT brg[CHB];

    auto loadA = [&](int kt) {
#pragma unroll
        for (int i = 0; i < CHA; ++i) {
            int c = i * 256 + tid;
            int r = c / ACPR, k = c % ACPR;
            if constexpr (AMODE == 0) {
                const __bf16* A = (const __bf16*)Ap;
                arg[i] = *(const uint4*)(A + (size_t)(m0 + r) * lda + kt + k * 8);
            } else {
                const float* A = (const float*)Ap;
                arg[i] = *(const f32x4*)(A + (size_t)(m0 + r) * lda + kt + k * 4);
            }
        }
    };
    auto loadB = [&](int kt) {
#pragma unroll
        for (int i = 0; i < CHB; ++i) {
            int c = i * 256 + tid;
            int r = c / BCPR, k = c % BCPR;
            if constexpr (BMODE == 0) {
                const __bf16* B = (const __bf16*)Bp;
                brg[i] = *(const uint4*)(B + (size_t)(n0 + r) * ldb + kt + k * 8);
            } else {
                const float* B = (const float*)Bp;
                brg[i] = *(const f32x4*)(B + (size_t)(n0 + r) * ldb + kt + k * 4);
            }
        }
    };
    auto writeA = [&]() {
#pragma unroll
        for (int i = 0; i < CHA; ++i) {
            int c = i * 256 + tid;
            int r = c / ACPR, k = c % ACPR;
            if constexpr (AMODE == 0) {
                *(uint4*)&As[r * LDSK + k * 8] = arg[i];
            } else {
                bf16x4 hv;
#pragma unroll
                for (int e = 0; e < 4; ++e) hv[e] = (__bf16)arg[i][e];
                *(bf16x4*)&As[r * LDSK + k * 4] = hv;
                if constexpr (AMODE == 2) {
                    bf16x4 lv;
#pragma unroll
                    for (int e = 0; e < 4; ++e)
                        lv[e] = (__bf16)(arg[i][e] - (float)hv[e]);
                    *(bf16x4*)&As2[r * LDSK + k * 4] = lv;
                }
            }
        }
    };
    auto writeB = [&]() {
#pragma unroll
        for (int i = 0; i < CHB; ++i) {
            int c = i * 256 + tid;
            int r = c / BCPR, k = c % BCPR;
            if constexpr (BMODE == 0) {
                *(uint4*)&Bs[r * LDSK + k * 8] = brg[i];
            } else {
                bf16x4 hv;
#pragma unroll
                for (int e = 0; e < 4; ++e) hv[e] = (__bf16)brg[i][e];
                *(bf16x4*)&Bs[r * LDSK + k * 4] = hv;
                if constexpr (BMODE == 2) {
                    bf16x4 lv;
#pragma unroll
                    for (int e = 0; e < 4; ++e)
                        lv[e] = (__bf16)(brg[i][e] - (float)hv[e]);
                    *(bf16x4*)&Bs2[r * LDSK + k * 4] = lv;
                }
            }
        }
    };
    auto compute = [&]() {
#pragma unroll
        for (int ks = 0; ks < BK / 32; ++ks) {
            const int kc = ks * 32 + kq * 8;
            bf16x8 af[FM], bfg[FN];
#pragma unroll
            for (int fm = 0; fm < FM; ++fm)
                af[fm] = *(const bf16x8*)&As[(wm * WM + fm * 16 + fr) * LDSK + kc];
#pragma unroll
            for (int fn = 0; fn < FN; ++fn)
                bfg[fn] = *(const bf16x8*)&Bs[(wn * WN + fn * 16 + fr) * LDSK + kc];
            if constexpr (AMODE == 2 && BMODE == 2) {
                bf16x8 al[FM], bl[FN];
#pragma unroll
                for (int fm = 0; fm < FM; ++fm)
                    al[fm] = *(const bf16x8*)&As2[(wm * WM + fm * 16 + fr) * LDSK + kc];
#pragma unroll
                for (int fn = 0; fn < FN; ++fn)
                    bl[fn] = *(const bf16x8*)&Bs2[(wn * WN + fn * 16 + fr) * LDSK + kc];
#pragma unroll
                for (int fm = 0; fm < FM; ++fm)
#pragma unroll
                    for (int fn = 0; fn < FN; ++fn) {
                        acc[fm][fn] = __builtin_amdgcn_mfma_f32_16x16x32_bf16(
                            al[fm], bfg[fn], acc[fm][fn], 0, 0, 0);
                        acc[fm][fn] = __builtin_amdgcn_mfma_f32_16x16x32_bf16(
                            af[fm], bl[fn], acc[fm][fn], 0, 0, 0);
                        acc[fm][fn] = __builtin_amdgcn_mfma_f32_16x16x32_bf16(
                            af[fm], bfg[fn], acc[fm][fn], 0, 0, 0);
                    }
            } else if constexpr (AMODE == 2) {
                bf16x8 al[FM];
#pragma unroll
                for (int fm = 0; fm < FM; ++fm)
                    al[fm] = *(const bf16x8*)&As2[(wm * WM + fm * 16 + fr) * LDSK + kc];
#pragma unroll
                for (int fm = 0; fm < FM; ++fm)
#pragma unroll
                    for (int fn = 0; fn < FN; ++fn) {
                        acc[fm][fn] = __builtin_amdgcn_mfma_f32_16x16x32_bf16(
                            al[fm], bfg[fn], acc[fm][fn], 0, 0, 0);
                        acc[fm][fn] = __builtin_amdgcn_mfma_f32_16x16x32_bf16(
                            af[fm], bfg[fn], acc[fm][fn], 0, 0, 0);
                    }
            } else if constexpr (BMODE == 2) {
                bf16x8 bl[FN];
#pragma unroll
                for (int fn = 0; fn < FN; ++fn)
                    bl[fn] = *(const bf16x8*)&Bs2[(wn * WN + fn * 16 + fr) * LDSK + kc];
#pragma unroll
                for (int fm = 0; fm < FM; ++fm)
#pragma unroll
                    for (int fn = 0; fn < FN; ++fn) {
                        acc[fm][fn] = __builtin_amdgcn_mfma_f32_16x16x32_bf16(
                            af[fm], bl[fn], acc[fm][fn], 0, 0, 0);
                        acc[fm][fn] = __builtin_amdgcn_mfma_f32_16x16x32_bf16(
                            af[fm], bfg[fn], acc[fm][fn], 0, 0, 0);
                    }
            } else {
#pragma unroll
                for (int fm = 0; fm < FM; ++fm)
#pragma unroll
                    for (int fn = 0; fn < FN; ++fn)
                        acc[fm][fn] = __builtin_amdgcn_mfma_f32_16x16x32_bf16(
                            af[fm], bfg[fn], acc[fm][fn], 0, 0, 0);
            }
        }
    };

    loadA(kb);
    loadB(kb);

    for (int kt = kb; kt < ke; kt += BK) {
        writeA();
        writeB();
        __syncthreads();
        if (kt + BK < ke) {
            loadA(kt + BK);
            loadB(kt + BK);
        }
        compute();
        __syncthreads();
    }

    const int rbase = m0 + wm * WM, cbase = n0 + wn * WN;
#pragma unroll
    for (int fm = 0; fm < FM; ++fm) {
#pragma unroll
        for (int fn = 0; fn < FN; ++fn) {
            int row = rbase + fm * 16 + (lane >> 4) * 4;
            int col = cbase + fn * 16 + (lane & 15);
            f32x4 v = acc[fm][fn];
            if (EPI == 0) {
                int split = N / 2;
                __bf16* d = (col < split) ? (__bf16*)out0 : (__bf16*)out1;
                int cc = (col < split) ? col : col - split;
#pragma unroll
                for (int j = 0; j < 4; ++j)
                    d[(size_t)(row + j) * ldc + cc] = (__bf16)v[j];
            } else if (EPI == 1) {
                float bz = bias[col];
                __bf16* d = (__bf16*)out0;
#pragma unroll
                for (int j = 0; j < 4; ++j) {
                    float t = v[j] + bz;
                    t = (t > 20.f) ? t : log1pf(__expf(t));
                    d[(size_t)(row + j) * ldc + col] = (__bf16)t;
                }
            } else if (EPI == 2) {
                float* d = (float*)out0;
#pragma unroll
                for (int j = 0; j < 4; ++j)
                    atomicAdd(&d[(size_t)(row + j) * ldc + col], v[j]);
            } else {   // EPI == 4: split-K partial slab (f32)
                float* d = (float*)out0 + (size_t)blockIdx.z * M * ldc;
#pragma unroll
                for (int j = 0; j < 4; ++j)
                    d[(size_t)(row + j) * ldc + col] = v[j];
            }
        }
    }
}

// ---------------------------------------------------------------------------
// out[i] = p[i] + p[slab + i]  (split-K=2 reduce), vectorized
__global__ __launch_bounds__(256) void reduce2_f32(
    const float* __restrict__ p, float* __restrict__ out, int n4)
{
    int i = blockIdx.x * 256 + threadIdx.x;
    if (i < n4) {
        f32x4 a = ((const f32x4*)p)[i];
        f32x4 b = ((const f32x4*)(p + (size_t)L_SEQ * D_MODEL))[i];
        ((f32x4*)out)[i] = a + b;
    }
}

// ---------------------------------------------------------------------------
// Depthwise conv (width 4, left-pad 3) + SiLU.  x, xc: [L][D_INNER] bf16.
// conv_state[d][j] = x[1020+j][d] (f32, from bf16 x). Also zeroes dbl.
// ---------------------------------------------------------------------------
__global__ __launch_bounds__(256) void conv_silu(
    const __bf16* __restrict__ x, const float* __restrict__ cw,
    const float* __restrict__ cb, __bf16* __restrict__ xc,
    float* __restrict__ conv_state, float* __restrict__ dbl)
{
    int idx = blockIdx.x * 256 + threadIdx.x;
    if (idx < L_SEQ * 128 / 4)
        ((f32x4*)dbl)[idx] = f32x4{0.f, 0.f, 0.f, 0.f};
    int l  = idx / (D_INNER / 4);
    int d4 = (idx % (D_INNER / 4)) * 4;
    const bf16x4 bz = bf16x4{(__bf16)0.f, (__bf16)0.f, (__bf16)0.f, (__bf16)0.f};
    bf16x4 u0 = *(const bf16x4*)&x[(size_t)l * D_INNER + d4];
    bf16x4 u1 = (l >= 1) ? *(const bf16x4*)&x[(size_t)(l - 1) * D_INNER + d4] : bz;
    bf16x4 u2 = (l >= 2) ? *(const bf16x4*)&x[(size_t)(l - 2) * D_INNER + d4] : bz;
    bf16x4 u3 = (l >= 3) ? *(const bf16x4*)&x[(size_t)(l - 3) * D_INNER + d4] : bz;
    bf16x4 r;
#pragma unroll
    for (int i = 0; i < 4; ++i) {
        int d = d4 + i;
        float w0 = cw[d * 4 + 0], w1 = cw[d * 4 + 1];
        float w2 = cw[d * 4 + 2], w3 = cw[d * 4 + 3];
        float v = cb[d] + w3 * (float)u0[i] + w2 * (float)u1[i]
                        + w1 * (float)u2[i] + w0 * (float)u3[i];
        r[i] = (__bf16)(v / (1.f + __expf(-v)));
    }
    *(bf16x4*)&xc[(size_t)l * D_INNER + d4] = r;
    if (l == L_SEQ - 1) {
#pragma unroll
        for (int i = 0; i < 4; ++i) {
            int d = d4 + i;
            conv_state[d * 4 + 3] = (float)u0[i];
            conv_state[d * 4 + 2] = (float)u1[i];
            conv_state[d * 4 + 1] = (float)u2[i];
            conv_state[d * 4 + 0] = (float)u3[i];
        }
    }
}

// ---------------------------------------------------------------------------
// Chunked scan, phase 1. Thread = d (lane-coalesced), block.y = chunk.
// delta, xc: [L][D] bf16.  All 16 n-states in registers.
// ---------------------------------------------------------------------------
__global__ __launch_bounds__(256) void scan_phase1(
    const __bf16* __restrict__ delta, const __bf16* __restrict__ xc,
    const float* __restrict__ dbl, const float* __restrict__ A_log,
    float* __restrict__ U, float* __restrict__ Aprod)
{
    int d = blockIdx.x * 256 + threadIdx.x;
    int c = blockIdx.y;
    float a[D_STATE], h[D_STATE], p[D_STATE];
#pragma unroll
    for (int n = 0; n < D_STATE; n += 4) {
        f32x4 av = *(const f32x4*)&A_log[d * D_STATE + n];
#pragma unroll
        for (int e = 0; e < 4; ++e) {
            a[n + e] = __expf(av[e]);
            h[n + e] = 0.f;
            p[n + e] = 1.f;
        }
    }
    int l0 = c * SCAN_CL;
    for (int i = 0; i < SCAN_CL; ++i) {
        int l = l0 + i;
        float dl = (float)delta[(size_t)l * D_INNER + d];
        float xv = (float)xc[(size_t)l * D_INNER + d];
        const float* Bp = dbl + l * 128 + DT_RANK;
        f32x4 B0 = *(const f32x4*)(Bp);
        f32x4 B1 = *(const f32x4*)(Bp + 4);
        f32x4 B2 = *(const f32x4*)(Bp + 8);
        f32x4 B3 = *(const f32x4*)(Bp + 12);
        float dx = dl * xv;
#pragma unroll
        for (int n = 0; n < D_STATE; ++n) {
            float Bv = (n < 4) ? B0[n] : (n < 8) ? B1[n - 4]
                     : (n < 12) ? B2[n - 8] : B3[n - 12];
            float dA = __expf(-dl * a[n]);
            h[n] = fmaf(dA, h[n], dx * Bv);
            p[n] *= dA;
        }
    }
    size_t base = (size_t)c * NCHAIN + (size_t)d * D_STATE;
#pragma unroll
    for (int n = 0; n < D_STATE; n += 4) {
        *(f32x4*)&U[base + n]     = f32x4{h[n], h[n+1], h[n+2], h[n+3]};
        *(f32x4*)&Aprod[base + n] = f32x4{p[n], p[n+1], p[n+2], p[n+3]};
    }
}

// ---------------------------------------------------------------------------
// Phase 2: per (d,n) serial combine over NC chunks; writes last_state (f32).
// ---------------------------------------------------------------------------
__global__ __launch_bounds__(256) void scan_phase2(
    const float* __restrict__ U, const float* __restrict__ Aprod,
    float* __restrict__ Hin, float* __restrict__ last_state)
{
    int r = blockIdx.x * 256 + threadIdx.x;
    float hin = 0.f;
#pragma unroll
    for (int c = 0; c < SCAN_NC; ++c) {
        Hin[c * NCHAIN + r] = hin;
        hin = fmaf(Aprod[c * NCHAIN + r], hin, U[c * NCHAIN + r]);
    }
    last_state[r] = hin;
}

// ---------------------------------------------------------------------------
// Phase 3: seeded local scan; y = (sum_n h*C + D*xc)*silu(z) -> bf16 [L][D].
// ---------------------------------------------------------------------------
__global__ __launch_bounds__(256) void scan_phase3(
    const __bf16* __restrict__ delta, const __bf16* __restrict__ xc,
    const __bf16* __restrict__ z, const float* __restrict__ dbl,
    const float* __restrict__ A_log, const float* __restrict__ Dp,
    const float* __restrict__ Hin, __bf16* __restrict__ y)
{
    int d = blockIdx.x * 256 + threadIdx.x;
    int c = blockIdx.y;
    float a[D_STATE], h[D_STATE];
    size_t hbase = (size_t)c * NCHAIN + (size_t)d * D_STATE;
#pragma unroll
    for (int n = 0; n < D_STATE; n += 4) {
        f32x4 av = *(const f32x4*)&A_log[d * D_STATE + n];
        f32x4 hv = *(const f32x4*)&Hin[hbase + n];
#pragma unroll
        for (int e = 0; e < 4; ++e) {
            a[n + e] = __expf(av[e]);
            h[n + e] = hv[e];
        }
    }
    float Dv = Dp[d];
    int l0 = c * SCAN_CL;
    for (int i = 0; i < SCAN_CL; ++i) {
        int l = l0 + i;
        float dl = (float)delta[(size_t)l * D_INNER + d];
        float xv = (float)xc[(size_t)l * D_INNER + d];
        float zv = (float)z[(size_t)l * D_INNER + d];
        const float* Bp = dbl + l * 128 + DT_RANK;
        f32x4 B0 = *(const f32x4*)(Bp);
        f32x4 B1 = *(const f32x4*)(Bp + 4);
        f32x4 B2 = *(const f32x4*)(Bp + 8);
        f32x4 B3 = *(const f32x4*)(Bp + 12);
        f32x4 C0 = *(const f32x4*)(Bp + 16);
        f32x4 C1 = *(const f32x4*)(Bp + 20);
        f32x4 C2 = *(const f32x4*)(Bp + 24);
        f32x4 C3 = *(const f32x4*)(Bp + 28);
        float dx = dl * xv;
        float yv = 0.f;
#pragma unroll
        for (int n = 0; n < D_STATE; ++n) {
            float Bv = (n < 4) ? B0[n] : (n < 8) ? B1[n - 4]
                     : (n < 12) ? B2[n - 8] : B3[n - 12];
            float Cv = (n < 4) ? C0[n] : (n < 8) ? C1[n - 4]
                     : (n < 12) ? C2[n - 8] : C3[n - 12];
            float dA = __expf(-dl * a[n]);
            h[n] = fmaf(dA, h[n], dx * Bv);
            yv = fmaf(h[n], Cv, yv);
        }
        float sz = zv / (1.f + __expf(-zv));
        y[(size_t)l * D_INNER + d] = (__bf16)((yv + Dv * xv) * sz);
    }
}

// ---------------------------------------------------------------------------
extern "C" void kernel_launch(void* const* d_in, const int* in_sizes, int n_in,
                              void* d_out, int out_size, void* d_ws, size_t ws_size,
                              hipStream_t stream)
{
    const float* hs    = (const float*)d_in[0];
    const float* Win   = (const float*)d_in[1];
    const float* cw    = (const float*)d_in[2];
    const float* cb    = (const float*)d_in[3];
    const float* Wx    = (const float*)d_in[4];
    const float* Wdt   = (const float*)d_in[5];
    const float* dtb   = (const float*)d_in[6];
    const float* Wout  = (const float*)d_in[7];
    const float* A_log = (const float*)d_in[8];
    const float* Dp    = (const float*)d_in[9];

    float* out        = (float*)d_out;
    float* conv_state = out + (size_t)L_SEQ * D_MODEL;
    float* last_state = conv_state + (size_t)D_INNER * 4;

    const size_t NEED = sizeof(float) * (size_t)SCRATCH_FLOATS;
    float* base;
    if (ws_size >= NEED) {
        base = (float*)d_ws;
    } else {
        void* sp = nullptr;
        hipGetSymbolAddress(&sp, HIP_SYMBOL(g_scratch));
        base = (float*)sp;
    }
    // bf16 intermediates: x, z, xc, delta, y = 5 x [L][D] bf16 (31.5 MB)
    __bf16* xB  = (__bf16*)base;
    __bf16* zB  = xB  + (size_t)L_SEQ * D_INNER;
    __bf16* xcB = zB  + (size_t)L_SEQ * D_INNER;
    __bf16* dlB = xcB + (size_t)L_SEQ * D_INNER;
    __bf16* yB  = dlB + (size_t)L_SEQ * D_INNER;
    float* dbl  = (float*)(yB + (size_t)L_SEQ * D_INNER);  // [1024][128]
    float* Ubuf = dbl  + (size_t)L_SEQ * 128;
    float* Abuf = Ubuf + (size_t)SCAN_NC * NCHAIN;
    float* Hbuf = Abuf + (size_t)SCAN_NC * NCHAIN;
    float* slab = Hbuf + (size_t)SCAN_NC * NCHAIN;         // [2][L][D_MODEL]

    // K1: xz = hs @ Win^T -> x (bf16), z (bf16).
    // BK=64, BM128/BN64, SWZY=12, grid 768. (proven best geometry)
    gemm_bt<128, 64, 64, 1, 1, 0, 12><<<dim3(768), 256, 0, stream>>>(
        hs, Win, xB, zB, nullptr, L_SEQ, 2 * D_INNER, D_MODEL, D_MODEL, D_MODEL, D_INNER);

    // K2: conv + silu -> xc (bf16); conv_state (f32); zeroes dbl
    conv_silu<<<dim3(L_SEQ * D_INNER / 4 / 256), 256, 0, stream>>>(
        xB, cw, cb, xcB, conv_state, dbl);

    // K3: dbl = xc @ Wx^T (A bf16-direct, B hi/lo f32; split-K 24, atomic
    // into L2-resident 0.5 MB dbl -- atomics OK here)
    gemm_bt<64, 128, 32, 0, 2, 2><<<dim3(16, 1, 24), 256, 0, stream>>>(
        xcB, Wx, dbl, nullptr, nullptr, L_SEQ, 128, D_INNER, D_INNER, D_INNER, 128);

    // K4: delta = softplus(dt @ Wdt^T + b) -> bf16. BK=96 single tile.
    gemm_bt<64, 64, 96, 2, 2, 1><<<dim3(16, 48), 256, 0, stream>>>(
        dbl, Wdt, dlB, nullptr, dtb, L_SEQ, D_INNER, DT_RANK, 128, DT_RANK, D_INNER);

    // K5: chunked scan (3 phases) -> y (bf16), last_state
    scan_phase1<<<dim3(D_INNER / 256, SCAN_NC), 256, 0, stream>>>(
        dlB, xcB, dbl, A_log, Ubuf, Abuf);
    scan_phase2<<<dim3(NCHAIN / 256), 256, 0, stream>>>(
        Ubuf, Abuf, Hbuf, last_state);
    scan_phase3<<<dim3(D_INNER / 256, SCAN_NC), 256, 0, stream>>>(
        dlB, xcB, zB, dbl, A_log, Dp, Hbuf, yB);

    // K7: out = y @ Wout^T (A bf16-direct), split-K=2 -> f32 slabs; reduce.
    gemm_bt<64, 64, 64, 0, 1, 4><<<dim3(16, 24, 2), 256, 0, stream>>>(
        yB, Wout, slab, nullptr, nullptr, L_SEQ, D_MODEL, D_INNER, D_INNER, D_INNER, D_MODEL);
    reduce2_f32<<<dim3(L_SEQ * D_MODEL / 4 / 256), 256, 0, stream>>>(
        slab, out, L_SEQ * D_MODEL / 4);
}

// Round 20
// 198.040 us; speedup vs baseline: 1.0121x; 1.0071x over previous
//
#include <hip/hip_runtime.h>

using f32x4  = __attribute__((ext_vector_type(4))) float;
using bf16x4 = __attribute__((ext_vector_type(4))) __bf16;
using bf16x8 = __attribute__((ext_vector_type(8))) __bf16;

#define L_SEQ 1024
#define D_MODEL 1536
#define D_INNER 3072
#define DT_RANK 96
#define D_STATE 16

#define SCAN_NC 32          // chunks over L
#define SCAN_CL (L_SEQ / SCAN_NC)     // 32
#define NCHAIN  (D_INNER * D_STATE)   // 49152 (d,n) chains

// Static fallback scratch: 5 bf16 [L][D] + dbl + 3 chain bufs + K7 slab.
#define SCRATCH_FLOATS (4 * L_SEQ * D_INNER + L_SEQ * 128 + 3 * SCAN_NC * NCHAIN)
__device__ __align__(16) float g_scratch[SCRATCH_FLOATS];

template <bool B16> struct RegT { using T = f32x4; };
template <> struct RegT<true> { using T = uint4; };

// ---------------------------------------------------------------------------
// BT GEMM: C[M][N] = sum_k A[M][K] * B[N][K]  (B N-major).
// 1-deep register prefetch + row-contiguous lane mapping; compute() iterates
// BK/32 MFMA sub-steps per staged tile.
// AMODE/BMODE: 0 = input already bf16 (16B LDS copies, no cvt);
//              1 = f32 -> bf16; 2 = f32 -> (hi,lo) bf16 pair.
// EPI: 0 = split bf16 stores (x|z); 1 = softplus(acc+bias[col]) bf16;
//      2 = atomicAdd f32 (ONLY for small L2-resident targets — r18 lesson);
//      4 = split-K partial f32 slab (out0 + z*M*ldc), reduce separately.
// SWZY>0: x-grid = 8*SWZY*(M/BM), XCD-chunked N (bijective); blockIdx.z
//         still available for split-K.
// ---------------------------------------------------------------------------
template <int BM, int BN, int BK, int AMODE, int BMODE, int EPI, int SWZY = 0>
__global__ __launch_bounds__(256) void gemm_bt(
    const void* __restrict__ Ap, const void* __restrict__ Bp,
    void* __restrict__ out0, void* __restrict__ out1,
    const float* __restrict__ bias,
    int M, int N, int K, int lda, int ldb, int ldc)
{
    constexpr int LDSK = BK + 8;
    constexpr int WM = BM / 2, WN = BN / 2;
    constexpr int FM = WM / 16, FN = WN / 16;
    constexpr int AEPT = (AMODE == 0) ? 8 : 4;
    constexpr int BEPT = (BMODE == 0) ? 8 : 4;
    constexpr int CHA = (BM * BK / 256) / AEPT;
    constexpr int CHB = (BN * BK / 256) / BEPT;
    constexpr int ACPR = BK / AEPT, BCPR = BK / BEPT;
    using ART = typename RegT<AMODE == 0>::T;
    using BRT = typename RegT<BMODE == 0>::T;
    __shared__ __align__(16) __bf16 As [BM * LDSK];
    __shared__ __align__(16) __bf16 As2[(AMODE == 2) ? BM * LDSK : 8];
    __shared__ __align__(16) __bf16 Bs [BN * LDSK];
    __shared__ __align__(16) __bf16 Bs2[(BMODE == 2) ? BN * LDSK : 8];

    const int tid  = threadIdx.x;
    const int lane = tid & 63;
    const int wid  = tid >> 6;
    const int wm = wid >> 1, wn = wid & 1;

    int m0, n0;
    if constexpr (SWZY > 0) {
        int b   = blockIdx.x;
        int xcd = b & 7;
        int j   = b >> 3;
        m0 = (j / SWZY) * BM;
        n0 = (xcd * SWZY + (j % SWZY)) * BN;
    } else {
        m0 = blockIdx.x * BM;
        n0 = blockIdx.y * BN;
    }

    const int nkt = (K + BK - 1) / BK;
    const int per = (nkt + (int)gridDim.z - 1) / (int)gridDim.z;
    const int kb  = blockIdx.z * per * BK;
    const int ke  = min(K, kb + per * BK);

    f32x4 acc[FM][FN];
#pragma unroll
    for (int i = 0; i < FM; ++i)
#pragma unroll
        for (int j = 0; j < FN; ++j) acc[i][j] = f32x4{0.f, 0.f, 0.f, 0.f};

    const int fr = lane & 15, kq = lane >> 4;

    ART arg[CHA];
    BRT brg[CHB];

    auto loadA = [&](int kt) {
#pragma unroll
        for (int i = 0; i < CHA; ++i) {
            int c = i * 256 + tid;
            int r = c / ACPR, k = c % ACPR;
            if constexpr (AMODE == 0) {
                const __bf16* A = (const __bf16*)Ap;
                arg[i] = *(const uint4*)(A + (size_t)(m0 + r) * lda + kt + k * 8);
            } else {
                const float* A = (const float*)Ap;
                arg[i] = *(const f32x4*)(A + (size_t)(m0 + r) * lda + kt + k * 4);
            }
        }
    };
    auto loadB = [&](int kt) {
#pragma unroll
        for (int i = 0; i < CHB; ++i) {
            int c = i * 256 + tid;
            int r = c / BCPR, k = c % BCPR;
            if constexpr (BMODE == 0) {
                const __bf16* B = (const __bf16*)Bp;
                brg[i] = *(const uint4*)(B + (size_t)(n0 + r) * ldb + kt + k * 8);
            } else {
                const float* B = (const float*)Bp;
                brg[i] = *(const f32x4*)(B + (size_t)(n0 + r) * ldb + kt + k * 4);
            }
        }
    };
    auto writeA = [&]() {
#pragma unroll
        for (int i = 0; i < CHA; ++i) {
            int c = i * 256 + tid;
            int r = c / ACPR, k = c % ACPR;
            if constexpr (AMODE == 0) {
                *(uint4*)&As[r * LDSK + k * 8] = arg[i];
            } else {
                bf16x4 hv;
#pragma unroll
                for (int e = 0; e < 4; ++e) hv[e] = (__bf16)arg[i][e];
                *(bf16x4*)&As[r * LDSK + k * 4] = hv;
                if constexpr (AMODE == 2) {
                    bf16x4 lv;
#pragma unroll
                    for (int e = 0; e < 4; ++e)
                        lv[e] = (__bf16)(arg[i][e] - (float)hv[e]);
                    *(bf16x4*)&As2[r * LDSK + k * 4] = lv;
                }
            }
        }
    };
    auto writeB = [&]() {
#pragma unroll
        for (int i = 0; i < CHB; ++i) {
            int c = i * 256 + tid;
            int r = c / BCPR, k = c % BCPR;
            if constexpr (BMODE == 0) {
                *(uint4*)&Bs[r * LDSK + k * 8] = brg[i];
            } else {
                bf16x4 hv;
#pragma unroll
                for (int e = 0; e < 4; ++e) hv[e] = (__bf16)brg[i][e];
                *(bf16x4*)&Bs[r * LDSK + k * 4] = hv;
                if constexpr (BMODE == 2) {
                    bf16x4 lv;
#pragma unroll
                    for (int e = 0; e < 4; ++e)
                        lv[e] = (__bf16)(brg[i][e] - (float)hv[e]);
                    *(bf16x4*)&Bs2[r * LDSK + k * 4] = lv;
                }
            }
        }
    };
    auto compute = [&]() {
#pragma unroll
        for (int ks = 0; ks < BK / 32; ++ks) {
            const int kc = ks * 32 + kq * 8;
            bf16x8 af[FM], bfg[FN];
#pragma unroll
            for (int fm = 0; fm < FM; ++fm)
                af[fm] = *(const bf16x8*)&As[(wm * WM + fm * 16 + fr) * LDSK + kc];
#pragma unroll
            for (int fn = 0; fn < FN; ++fn)
                bfg[fn] = *(const bf16x8*)&Bs[(wn * WN + fn * 16 + fr) * LDSK + kc];
            if constexpr (AMODE == 2 && BMODE == 2) {
                bf16x8 al[FM], bl[FN];
#pragma unroll
                for (int fm = 0; fm < FM; ++fm)
                    al[fm] = *(const bf16x8*)&As2[(wm * WM + fm * 16 + fr) * LDSK + kc];
#pragma unroll
                for (int fn = 0; fn < FN; ++fn)
                    bl[fn] = *(const bf16x8*)&Bs2[(wn * WN + fn * 16 + fr) * LDSK + kc];
#pragma unroll
                for (int fm = 0; fm < FM; ++fm)
#pragma unroll
                    for (int fn = 0; fn < FN; ++fn) {
                        acc[fm][fn] = __builtin_amdgcn_mfma_f32_16x16x32_bf16(
                            al[fm], bfg[fn], acc[fm][fn], 0, 0, 0);
                        acc[fm][fn] = __builtin_amdgcn_mfma_f32_16x16x32_bf16(
                            af[fm], bl[fn], acc[fm][fn], 0, 0, 0);
                        acc[fm][fn] = __builtin_amdgcn_mfma_f32_16x16x32_bf16(
                            af[fm], bfg[fn], acc[fm][fn], 0, 0, 0);
                    }
            } else if constexpr (AMODE == 2) {
                bf16x8 al[FM];
#pragma unroll
                for (int fm = 0; fm < FM; ++fm)
                    al[fm] = *(const bf16x8*)&As2[(wm * WM + fm * 16 + fr) * LDSK + kc];
#pragma unroll
                for (int fm = 0; fm < FM; ++fm)
#pragma unroll
                    for (int fn = 0; fn < FN; ++fn) {
                        acc[fm][fn] = __builtin_amdgcn_mfma_f32_16x16x32_bf16(
                            al[fm], bfg[fn], acc[fm][fn], 0, 0, 0);
                        acc[fm][fn] = __builtin_amdgcn_mfma_f32_16x16x32_bf16(
                            af[fm], bfg[fn], acc[fm][fn], 0, 0, 0);
                    }
            } else if constexpr (BMODE == 2) {
                bf16x8 bl[FN];
#pragma unroll
                for (int fn = 0; fn < FN; ++fn)
                    bl[fn] = *(const bf16x8*)&Bs2[(wn * WN + fn * 16 + fr) * LDSK + kc];
#pragma unroll
                for (int fm = 0; fm < FM; ++fm)
#pragma unroll
                    for (int fn = 0; fn < FN; ++fn) {
                        acc[fm][fn] = __builtin_amdgcn_mfma_f32_16x16x32_bf16(
                            af[fm], bl[fn], acc[fm][fn], 0, 0, 0);
                        acc[fm][fn] = __builtin_amdgcn_mfma_f32_16x16x32_bf16(
                            af[fm], bfg[fn], acc[fm][fn], 0, 0, 0);
                    }
            } else {
#pragma unroll
                for (int fm = 0; fm < FM; ++fm)
#pragma unroll
                    for (int fn = 0; fn < FN; ++fn)
                        acc[fm][fn] = __builtin_amdgcn_mfma_f32_16x16x32_bf16(
                            af[fm], bfg[fn], acc[fm][fn], 0, 0, 0);
            }
        }
    };

    loadA(kb);
    loadB(kb);

    for (int kt = kb; kt < ke; kt += BK) {
        writeA();
        writeB();
        __syncthreads();
        if (kt + BK < ke) {
            loadA(kt + BK);
            loadB(kt + BK);
        }
        compute();
        __syncthreads();
    }

    const int rbase = m0 + wm * WM, cbase = n0 + wn * WN;
#pragma unroll
    for (int fm = 0; fm < FM; ++fm) {
#pragma unroll
        for (int fn = 0; fn < FN; ++fn) {
            int row = rbase + fm * 16 + (lane >> 4) * 4;
            int col = cbase + fn * 16 + (lane & 15);
            f32x4 v = acc[fm][fn];
            if (EPI == 0) {
                int split = N / 2;
                __bf16* d = (col < split) ? (__bf16*)out0 : (__bf16*)out1;
                int cc = (col < split) ? col : col - split;
#pragma unroll
                for (int j = 0; j < 4; ++j)
                    d[(size_t)(row + j) * ldc + cc] = (__bf16)v[j];
            } else if (EPI == 1) {
                float bz = bias[col];
                __bf16* d = (__bf16*)out0;
#pragma unroll
                for (int j = 0; j < 4; ++j) {
                    float t = v[j] + bz;
                    t = (t > 20.f) ? t : log1pf(__expf(t));
                    d[(size_t)(row + j) * ldc + col] = (__bf16)t;
                }
            } else if (EPI == 2) {
                float* d = (float*)out0;
#pragma unroll
                for (int j = 0; j < 4; ++j)
                    atomicAdd(&d[(size_t)(row + j) * ldc + col], v[j]);
            } else {   // EPI == 4: split-K partial slab (f32)
                float* d = (float*)out0 + (size_t)blockIdx.z * M * ldc;
#pragma unroll
                for (int j = 0; j < 4; ++j)
                    d[(size_t)(row + j) * ldc + col] = v[j];
            }
        }
    }
}

// ---------------------------------------------------------------------------
// out[i] = p[i] + p[slab + i]  (split-K=2 reduce), vectorized
__global__ __launch_bounds__(256) void reduce2_f32(
    const float* __restrict__ p, float* __restrict__ out, int n4)
{
    int i = blockIdx.x * 256 + threadIdx.x;
    if (i < n4) {
        f32x4 a = ((const f32x4*)p)[i];
        f32x4 b = ((const f32x4*)(p + (size_t)L_SEQ * D_MODEL))[i];
        ((f32x4*)out)[i] = a + b;
    }
}

// ---------------------------------------------------------------------------
// Depthwise conv (width 4, left-pad 3) + SiLU.  x, xc: [L][D_INNER] bf16.
// conv_state[d][j] = x[1020+j][d] (f32, from bf16 x). Also zeroes dbl.
// ---------------------------------------------------------------------------
__global__ __launch_bounds__(256) void conv_silu(
    const __bf16* __restrict__ x, const float* __restrict__ cw,
    const float* __restrict__ cb, __bf16* __restrict__ xc,
    float* __restrict__ conv_state, float* __restrict__ dbl)
{
    int idx = blockIdx.x * 256 + threadIdx.x;
    if (idx < L_SEQ * 128 / 4)
        ((f32x4*)dbl)[idx] = f32x4{0.f, 0.f, 0.f, 0.f};
    int l  = idx / (D_INNER / 4);
    int d4 = (idx % (D_INNER / 4)) * 4;
    const bf16x4 bz = bf16x4{(__bf16)0.f, (__bf16)0.f, (__bf16)0.f, (__bf16)0.f};
    bf16x4 u0 = *(const bf16x4*)&x[(size_t)l * D_INNER + d4];
    bf16x4 u1 = (l >= 1) ? *(const bf16x4*)&x[(size_t)(l - 1) * D_INNER + d4] : bz;
    bf16x4 u2 = (l >= 2) ? *(const bf16x4*)&x[(size_t)(l - 2) * D_INNER + d4] : bz;
    bf16x4 u3 = (l >= 3) ? *(const bf16x4*)&x[(size_t)(l - 3) * D_INNER + d4] : bz;
    bf16x4 r;
#pragma unroll
    for (int i = 0; i < 4; ++i) {
        int d = d4 + i;
        float w0 = cw[d * 4 + 0], w1 = cw[d * 4 + 1];
        float w2 = cw[d * 4 + 2], w3 = cw[d * 4 + 3];
        float v = cb[d] + w3 * (float)u0[i] + w2 * (float)u1[i]
                        + w1 * (float)u2[i] + w0 * (float)u3[i];
        r[i] = (__bf16)(v / (1.f + __expf(-v)));
    }
    *(bf16x4*)&xc[(size_t)l * D_INNER + d4] = r;
    if (l == L_SEQ - 1) {
#pragma unroll
        for (int i = 0; i < 4; ++i) {
            int d = d4 + i;
            conv_state[d * 4 + 3] = (float)u0[i];
            conv_state[d * 4 + 2] = (float)u1[i];
            conv_state[d * 4 + 1] = (float)u2[i];
            conv_state[d * 4 + 0] = (float)u3[i];
        }
    }
}

// ---------------------------------------------------------------------------
// Chunked scan, phase 1. Thread = d (lane-coalesced), block.y = chunk.
// delta, xc: [L][D] bf16.  All 16 n-states in registers.
// ---------------------------------------------------------------------------
__global__ __launch_bounds__(256) void scan_phase1(
    const __bf16* __restrict__ delta, const __bf16* __restrict__ xc,
    const float* __restrict__ dbl, const float* __restrict__ A_log,
    float* __restrict__ U, float* __restrict__ Aprod)
{
    int d = blockIdx.x * 256 + threadIdx.x;
    int c = blockIdx.y;
    float a[D_STATE], h[D_STATE], p[D_STATE];
#pragma unroll
    for (int n = 0; n < D_STATE; n += 4) {
        f32x4 av = *(const f32x4*)&A_log[d * D_STATE + n];
#pragma unroll
        for (int e = 0; e < 4; ++e) {
            a[n + e] = __expf(av[e]);
            h[n + e] = 0.f;
            p[n + e] = 1.f;
        }
    }
    int l0 = c * SCAN_CL;
    for (int i = 0; i < SCAN_CL; ++i) {
        int l = l0 + i;
        float dl = (float)delta[(size_t)l * D_INNER + d];
        float xv = (float)xc[(size_t)l * D_INNER + d];
        const float* Bp = dbl + l * 128 + DT_RANK;
        f32x4 B0 = *(const f32x4*)(Bp);
        f32x4 B1 = *(const f32x4*)(Bp + 4);
        f32x4 B2 = *(const f32x4*)(Bp + 8);
        f32x4 B3 = *(const f32x4*)(Bp + 12);
        float dx = dl * xv;
#pragma unroll
        for (int n = 0; n < D_STATE; ++n) {
            float Bv = (n < 4) ? B0[n] : (n < 8) ? B1[n - 4]
                     : (n < 12) ? B2[n - 8] : B3[n - 12];
            float dA = __expf(-dl * a[n]);
            h[n] = fmaf(dA, h[n], dx * Bv);
            p[n] *= dA;
        }
    }
    size_t base = (size_t)c * NCHAIN + (size_t)d * D_STATE;
#pragma unroll
    for (int n = 0; n < D_STATE; n += 4) {
        *(f32x4*)&U[base + n]     = f32x4{h[n], h[n+1], h[n+2], h[n+3]};
        *(f32x4*)&Aprod[base + n] = f32x4{p[n], p[n+1], p[n+2], p[n+3]};
    }
}

// ---------------------------------------------------------------------------
// Phase 2: per (d,n) serial combine over NC chunks; writes last_state (f32).
// ---------------------------------------------------------------------------
__global__ __launch_bounds__(256) void scan_phase2(
    const float* __restrict__ U, const float* __restrict__ Aprod,
    float* __restrict__ Hin, float* __restrict__ last_state)
{
    int r = blockIdx.x * 256 + threadIdx.x;
    float hin = 0.f;
#pragma unroll
    for (int c = 0; c < SCAN_NC; ++c) {
        Hin[c * NCHAIN + r] = hin;
        hin = fmaf(Aprod[c * NCHAIN + r], hin, U[c * NCHAIN + r]);
    }
    last_state[r] = hin;
}

// ---------------------------------------------------------------------------
// Phase 3: seeded local scan; y = (sum_n h*C + D*xc)*silu(z) -> bf16 [L][D].
// ---------------------------------------------------------------------------
__global__ __launch_bounds__(256) void scan_phase3(
    const __bf16* __restrict__ delta, const __bf16* __restrict__ xc,
    const __bf16* __restrict__ z, const float* __restrict__ dbl,
    const float* __restrict__ A_log, const float* __restrict__ Dp,
    const float* __restrict__ Hin, __bf16* __restrict__ y)
{
    int d = blockIdx.x * 256 + threadIdx.x;
    int c = blockIdx.y;
    float a[D_STATE], h[D_STATE];
    size_t hbase = (size_t)c * NCHAIN + (size_t)d * D_STATE;
#pragma unroll
    for (int n = 0; n < D_STATE; n += 4) {
        f32x4 av = *(const f32x4*)&A_log[d * D_STATE + n];
        f32x4 hv = *(const f32x4*)&Hin[hbase + n];
#pragma unroll
        for (int e = 0; e < 4; ++e) {
            a[n + e] = __expf(av[e]);
            h[n + e] = hv[e];
        }
    }
    float Dv = Dp[d];
    int l0 = c * SCAN_CL;
    for (int i = 0; i < SCAN_CL; ++i) {
        int l = l0 + i;
        float dl = (float)delta[(size_t)l * D_INNER + d];
        float xv = (float)xc[(size_t)l * D_INNER + d];
        float zv = (float)z[(size_t)l * D_INNER + d];
        const float* Bp = dbl + l * 128 + DT_RANK;
        f32x4 B0 = *(const f32x4*)(Bp);
        f32x4 B1 = *(const f32x4*)(Bp + 4);
        f32x4 B2 = *(const f32x4*)(Bp + 8);
        f32x4 B3 = *(const f32x4*)(Bp + 12);
        f32x4 C0 = *(const f32x4*)(Bp + 16);
        f32x4 C1 = *(const f32x4*)(Bp + 20);
        f32x4 C2 = *(const f32x4*)(Bp + 24);
        f32x4 C3 = *(const f32x4*)(Bp + 28);
        float dx = dl * xv;
        float yv = 0.f;
#pragma unroll
        for (int n = 0; n < D_STATE; ++n) {
            float Bv = (n < 4) ? B0[n] : (n < 8) ? B1[n - 4]
                     : (n < 12) ? B2[n - 8] : B3[n - 12];
            float Cv = (n < 4) ? C0[n] : (n < 8) ? C1[n - 4]
                     : (n < 12) ? C2[n - 8] : C3[n - 12];
            float dA = __expf(-dl * a[n]);
            h[n] = fmaf(dA, h[n], dx * Bv);
            yv = fmaf(h[n], Cv, yv);
        }
        float sz = zv / (1.f + __expf(-zv));
        y[(size_t)l * D_INNER + d] = (__bf16)((yv + Dv * xv) * sz);
    }
}

// ---------------------------------------------------------------------------
extern "C" void kernel_launch(void* const* d_in, const int* in_sizes, int n_in,
                              void* d_out, int out_size, void* d_ws, size_t ws_size,
                              hipStream_t stream)
{
    const float* hs    = (const float*)d_in[0];
    const float* Win   = (const float*)d_in[1];
    const float* cw    = (const float*)d_in[2];
    const float* cb    = (const float*)d_in[3];
    const float* Wx    = (const float*)d_in[4];
    const float* Wdt   = (const float*)d_in[5];
    const float* dtb   = (const float*)d_in[6];
    const float* Wout  = (const float*)d_in[7];
    const float* A_log = (const float*)d_in[8];
    const float* Dp    = (const float*)d_in[9];

    float* out        = (float*)d_out;
    float* conv_state = out + (size_t)L_SEQ * D_MODEL;
    float* last_state = conv_state + (size_t)D_INNER * 4;

    const size_t NEED = sizeof(float) * (size_t)SCRATCH_FLOATS;
    float* base;
    if (ws_size >= NEED) {
        base = (float*)d_ws;
    } else {
        void* sp = nullptr;
        hipGetSymbolAddress(&sp, HIP_SYMBOL(g_scratch));
        base = (float*)sp;
    }
    // bf16 intermediates: x, z, xc, delta, y = 5 x [L][D] bf16 (31.5 MB)
    __bf16* xB  = (__bf16*)base;
    __bf16* zB  = xB  + (size_t)L_SEQ * D_INNER;
    __bf16* xcB = zB  + (size_t)L_SEQ * D_INNER;
    __bf16* dlB = xcB + (size_t)L_SEQ * D_INNER;
    __bf16* yB  = dlB + (size_t)L_SEQ * D_INNER;
    float* dbl  = (float*)(yB + (size_t)L_SEQ * D_INNER);  // [1024][128]
    float* Ubuf = dbl  + (size_t)L_SEQ * 128;
    float* Abuf = Ubuf + (size_t)SCAN_NC * NCHAIN;
    float* Hbuf = Abuf + (size_t)SCAN_NC * NCHAIN;
    float* slab = Hbuf + (size_t)SCAN_NC * NCHAIN;         // [2][L][D_MODEL]

    // K1: xz = hs @ Win^T -> x (bf16), z (bf16).
    // BK=64, BM128/BN64, SWZY=12, grid 768. (proven best geometry)
    gemm_bt<128, 64, 64, 1, 1, 0, 12><<<dim3(768), 256, 0, stream>>>(
        hs, Win, xB, zB, nullptr, L_SEQ, 2 * D_INNER, D_MODEL, D_MODEL, D_MODEL, D_INNER);

    // K2: conv + silu -> xc (bf16); conv_state (f32); zeroes dbl
    conv_silu<<<dim3(L_SEQ * D_INNER / 4 / 256), 256, 0, stream>>>(
        xB, cw, cb, xcB, conv_state, dbl);

    // K3: dbl = xc @ Wx^T (A bf16-direct, B hi/lo f32; split-K 24, atomic
    // into L2-resident 0.5 MB dbl)
    gemm_bt<64, 128, 32, 0, 2, 2><<<dim3(16, 1, 24), 256, 0, stream>>>(
        xcB, Wx, dbl, nullptr, nullptr, L_SEQ, 128, D_INNER, D_INNER, D_INNER, 128);

    // K4: delta = softplus(dt @ Wdt^T + b) -> bf16. BK=96 single tile.
    gemm_bt<64, 64, 96, 2, 2, 1><<<dim3(16, 48), 256, 0, stream>>>(
        dbl, Wdt, dlB, nullptr, dtb, L_SEQ, D_INNER, DT_RANK, 128, DT_RANK, D_INNER);

    // K5: chunked scan (3 phases) -> y (bf16), last_state
    scan_phase1<<<dim3(D_INNER / 256, SCAN_NC), 256, 0, stream>>>(
        dlB, xcB, dbl, A_log, Ubuf, Abuf);
    scan_phase2<<<dim3(NCHAIN / 256), 256, 0, stream>>>(
        Ubuf, Abuf, Hbuf, last_state);
    scan_phase3<<<dim3(D_INNER / 256, SCAN_NC), 256, 0, stream>>>(
        dlB, xcB, zB, dbl, A_log, Dp, Hbuf, yB);

    // K7: out = y @ Wout^T (A bf16-direct), split-K=2 -> f32 slabs; reduce.
    // SWZY=3: x-grid 384 = 8 XCD * 3 N-chunks * 16 M-blocks; per-XCD Wout
    // chunk 1.18 MB -> L2-resident (fixes r19's 80 MB FETCH re-reads).
    gemm_bt<64, 64, 64, 0, 1, 4, 3><<<dim3(384, 1, 2), 256, 0, stream>>>(
        yB, Wout, slab, nullptr, nullptr, L_SEQ, D_MODEL, D_INNER, D_INNER, D_INNER, D_MODEL);
    reduce2_f32<<<dim3(L_SEQ * D_MODEL / 4 / 256), 256, 0, stream>>>(
        slab, out, L_SEQ * D_MODEL / 4);
}

// Round 21
// 184.892 us; speedup vs baseline: 1.0840x; 1.0711x over previous
//
#include <hip/hip_runtime.h>

using f32x4  = __attribute__((ext_vector_type(4))) float;
using bf16x4 = __attribute__((ext_vector_type(4))) __bf16;
using bf16x8 = __attribute__((ext_vector_type(8))) __bf16;

#define L_SEQ 1024
#define D_MODEL 1536
#define D_INNER 3072
#define DT_RANK 96
#define D_STATE 16

#define SCAN_NC 32          // chunks over L
#define SCAN_CL (L_SEQ / SCAN_NC)     // 32
#define NCHAIN  (D_INNER * D_STATE)   // 49152 (d,n) chains

// Static fallback scratch: 4x[L][D] + dbl + 3x[NC][NCHAIN] f32  (~70 MB)
#define SCRATCH_FLOATS (4 * L_SEQ * D_INNER + L_SEQ * 128 + 3 * SCAN_NC * NCHAIN)
__device__ __align__(16) float g_scratch[SCRATCH_FLOATS];

// ---------------------------------------------------------------------------
// BT GEMM, all-f32 I/O: C[M][N] = sum_k A[M][K] * B[N][K]  (B is N-major f32)
// 1-deep register prefetch + row-contiguous lane mapping. compute() iterates
// BK/32 MFMA sub-steps per staged tile (BK amortizes barriers/vmcnt drains).
// 128x64 tile is the proven AI sweet spot. Both large GEMMs plateau ~61us in
// this 2-barrier structure (probed: depth, BK, BM, BN, swizzle, dtype).
// AMODE/BMODE: 1 = plain bf16; 2 = (hi,lo) bf16 pair -> 3 MFMAs per k-step.
// EPI: 0 split f32 store (x|z); 1 softplus(acc+bias[col]); 2 atomicAdd
//      (L2-resident targets only); 4 split-K partial slab; 5 softplus+row.
// SWZY>0: x-grid = 8*SWZY*(M/BM), XCD-chunked N (bijective); blockIdx.z
//         remains split-K.
// ---------------------------------------------------------------------------
template <int BM, int BN, int BK, int AMODE, int BMODE, int EPI, int SWZY = 0>
__global__ __launch_bounds__(256) void gemm_bt(
    const float* __restrict__ Ap, const float* __restrict__ Bp,
    float* __restrict__ out0, float* __restrict__ out1,
    const float* __restrict__ bias,
    int M, int N, int K, int lda, int ldb, int ldc)
{
    constexpr int LDSK = BK + 8;
    constexpr int WM = BM / 2, WN = BN / 2;
    constexpr int FM = WM / 16, FN = WN / 16;
    constexpr int CHA = (BM * BK / 256) / 4;   // f32x4 chunks per thread
    constexpr int CHB = (BN * BK / 256) / 4;
    constexpr int CPR = BK / 4;                // chunks per row
    __shared__ __align__(16) __bf16 As [BM * LDSK];
    __shared__ __align__(16) __bf16 As2[(AMODE == 2) ? BM * LDSK : 8];
    __shared__ __align__(16) __bf16 Bs [BN * LDSK];
    __shared__ __align__(16) __bf16 Bs2[(BMODE == 2) ? BN * LDSK : 8];

    const int tid  = threadIdx.x;
    const int lane = tid & 63;
    const int wid  = tid >> 6;
    const int wm = wid >> 1, wn = wid & 1;

    int m0, n0;
    if constexpr (SWZY > 0) {
        int b   = blockIdx.x;
        int xcd = b & 7;
        int j   = b >> 3;
        m0 = (j / SWZY) * BM;
        n0 = (xcd * SWZY + (j % SWZY)) * BN;
    } else {
        m0 = blockIdx.x * BM;
        n0 = blockIdx.y * BN;
    }

    const int nkt = (K + BK - 1) / BK;
    const int per = (nkt + (int)gridDim.z - 1) / (int)gridDim.z;
    const int kb  = blockIdx.z * per * BK;
    const int ke  = min(K, kb + per * BK);

    f32x4 acc[FM][FN];
#pragma unroll
    for (int i = 0; i < FM; ++i)
#pragma unroll
        for (int j = 0; j < FN; ++j) acc[i][j] = f32x4{0.f, 0.f, 0.f, 0.f};

    const int fr = lane & 15, kq = lane >> 4;

    f32x4 arg[CHA], brg[CHB];

    auto loadA = [&](int kt) {
#pragma unroll
        for (int i = 0; i < CHA; ++i) {
            int c = i * 256 + tid;
            int r = c / CPR, k4 = c % CPR;
            arg[i] = *(const f32x4*)(Ap + (size_t)(m0 + r) * lda + kt + k4 * 4);
        }
    };
    auto loadB = [&](int kt) {
#pragma unroll
        for (int i = 0; i < CHB; ++i) {
            int c = i * 256 + tid;
            int r = c / CPR, k4 = c % CPR;
            brg[i] = *(const f32x4*)(Bp + (size_t)(n0 + r) * ldb + kt + k4 * 4);
        }
    };
    auto writeA = [&]() {
#pragma unroll
        for (int i = 0; i < CHA; ++i) {
            int c = i * 256 + tid;
            int r = c / CPR, k4 = c % CPR;
            bf16x4 hv;
#pragma unroll
            for (int e = 0; e < 4; ++e) hv[e] = (__bf16)arg[i][e];
            *(bf16x4*)&As[r * LDSK + k4 * 4] = hv;
            if constexpr (AMODE == 2) {
                bf16x4 lv;
#pragma unroll
                for (int e = 0; e < 4; ++e)
                    lv[e] = (__bf16)(arg[i][e] - (float)hv[e]);
                *(bf16x4*)&As2[r * LDSK + k4 * 4] = lv;
            }
        }
    };
    auto writeB = [&]() {
#pragma unroll
        for (int i = 0; i < CHB; ++i) {
            int c = i * 256 + tid;
            int r = c / CPR, k4 = c % CPR;
            bf16x4 hv;
#pragma unroll
            for (int e = 0; e < 4; ++e) hv[e] = (__bf16)brg[i][e];
            *(bf16x4*)&Bs[r * LDSK + k4 * 4] = hv;
            if constexpr (BMODE == 2) {
                bf16x4 lv;
#pragma unroll
                for (int e = 0; e < 4; ++e)
                    lv[e] = (__bf16)(brg[i][e] - (float)hv[e]);
                *(bf16x4*)&Bs2[r * LDSK + k4 * 4] = lv;
            }
        }
    };
    auto compute = [&]() {
#pragma unroll
        for (int ks = 0; ks < BK / 32; ++ks) {
            const int kc = ks * 32 + kq * 8;
            bf16x8 af[FM], bfg[FN];
#pragma unroll
            for (int fm = 0; fm < FM; ++fm)
                af[fm] = *(const bf16x8*)&As[(wm * WM + fm * 16 + fr) * LDSK + kc];
#pragma unroll
            for (int fn = 0; fn < FN; ++fn)
                bfg[fn] = *(const bf16x8*)&Bs[(wn * WN + fn * 16 + fr) * LDSK + kc];
            if constexpr (AMODE == 2 && BMODE == 2) {
                bf16x8 al[FM], bl[FN];
#pragma unroll
                for (int fm = 0; fm < FM; ++fm)
                    al[fm] = *(const bf16x8*)&As2[(wm * WM + fm * 16 + fr) * LDSK + kc];
#pragma unroll
                for (int fn = 0; fn < FN; ++fn)
                    bl[fn] = *(const bf16x8*)&Bs2[(wn * WN + fn * 16 + fr) * LDSK + kc];
#pragma unroll
                for (int fm = 0; fm < FM; ++fm)
#pragma unroll
                    for (int fn = 0; fn < FN; ++fn) {
                        acc[fm][fn] = __builtin_amdgcn_mfma_f32_16x16x32_bf16(
                            al[fm], bfg[fn], acc[fm][fn], 0, 0, 0);
                        acc[fm][fn] = __builtin_amdgcn_mfma_f32_16x16x32_bf16(
                            af[fm], bl[fn], acc[fm][fn], 0, 0, 0);
                        acc[fm][fn] = __builtin_amdgcn_mfma_f32_16x16x32_bf16(
                            af[fm], bfg[fn], acc[fm][fn], 0, 0, 0);
                    }
            } else {
#pragma unroll
                for (int fm = 0; fm < FM; ++fm)
#pragma unroll
                    for (int fn = 0; fn < FN; ++fn)
                        acc[fm][fn] = __builtin_amdgcn_mfma_f32_16x16x32_bf16(
                            af[fm], bfg[fn], acc[fm][fn], 0, 0, 0);
            }
        }
    };

    loadA(kb);
    loadB(kb);

    for (int kt = kb; kt < ke; kt += BK) {
        writeA();                    // vmcnt wait on in-flight loads
        writeB();
        __syncthreads();             // LDS tile visible
        if (kt + BK < ke) {          // next tile's loads hide under compute
            loadA(kt + BK);
            loadB(kt + BK);
        }
        compute();
        __syncthreads();             // reads done before next ds_write
    }

    const int rbase = m0 + wm * WM, cbase = n0 + wn * WN;
#pragma unroll
    for (int fm = 0; fm < FM; ++fm) {
#pragma unroll
        for (int fn = 0; fn < FN; ++fn) {
            int row = rbase + fm * 16 + (lane >> 4) * 4;
            int col = cbase + fn * 16 + (lane & 15);
            f32x4 v = acc[fm][fn];
            if (EPI == 0) {
                int split = N / 2;
                float* d = (col < split) ? out0 : out1;
                int cc = (col < split) ? col : col - split;
#pragma unroll
                for (int j = 0; j < 4; ++j) d[(size_t)(row + j) * ldc + cc] = v[j];
            } else if (EPI == 1) {
                float bz = bias[col];
#pragma unroll
                for (int j = 0; j < 4; ++j) {
                    float t = v[j] + bz;
                    t = (t > 20.f) ? t : log1pf(__expf(t));
                    out0[(size_t)(row + j) * ldc + col] = t;
                }
            } else if (EPI == 2) {
#pragma unroll
                for (int j = 0; j < 4; ++j)
                    atomicAdd(&out0[(size_t)(row + j) * ldc + col], v[j]);
            } else if (EPI == 4) {
                float* d = out0 + (size_t)blockIdx.z * M * ldc;
#pragma unroll
                for (int j = 0; j < 4; ++j)
                    d[(size_t)(row + j) * ldc + col] = v[j];
            } else {   // EPI == 5: softplus + bias[row]
#pragma unroll
                for (int j = 0; j < 4; ++j) {
                    float t = v[j] + bias[row + j];
                    t = (t > 20.f) ? t : log1pf(__expf(t));
                    out0[(size_t)(row + j) * ldc + col] = t;
                }
            }
        }
    }
}

// ---------------------------------------------------------------------------
// out[i] = p[i] + p[slab + i]  (split-K=2 reduce), vectorized
__global__ __launch_bounds__(256) void reduce2_f32(
    const float* __restrict__ p, float* __restrict__ out, int n4)
{
    int i = blockIdx.x * 256 + threadIdx.x;
    if (i < n4) {
        f32x4 a = ((const f32x4*)p)[i];
        f32x4 b = ((const f32x4*)(p + (size_t)L_SEQ * D_MODEL))[i];
        ((f32x4*)out)[i] = a + b;
    }
}

// ---------------------------------------------------------------------------
// Depthwise conv (width 4, left-pad 3) + SiLU.  x, xc: [L][D_INNER] f32.
// conv_state[d][j] = x[1020+j][d]. Also zeroes dbl (runs before K3's atomics).
// ---------------------------------------------------------------------------
__global__ __launch_bounds__(256) void conv_silu(
    const float* __restrict__ x, const float* __restrict__ cw,
    const float* __restrict__ cb, float* __restrict__ xc,
    float* __restrict__ conv_state, float* __restrict__ dbl)
{
    int idx = blockIdx.x * 256 + threadIdx.x;
    const f32x4 zero = f32x4{0.f, 0.f, 0.f, 0.f};
    if (idx < L_SEQ * 128 / 4) ((f32x4*)dbl)[idx] = zero;   // zero dbl
    int l  = idx / (D_INNER / 4);
    int d4 = (idx % (D_INNER / 4)) * 4;
    f32x4 x0 = *(const f32x4*)&x[(size_t)l * D_INNER + d4];
    f32x4 x1 = (l >= 1) ? *(const f32x4*)&x[(size_t)(l - 1) * D_INNER + d4] : zero;
    f32x4 x2 = (l >= 2) ? *(const f32x4*)&x[(size_t)(l - 2) * D_INNER + d4] : zero;
    f32x4 x3 = (l >= 3) ? *(const f32x4*)&x[(size_t)(l - 3) * D_INNER + d4] : zero;
    f32x4 r;
#pragma unroll
    for (int i = 0; i < 4; ++i) {
        int d = d4 + i;
        float w0 = cw[d * 4 + 0], w1 = cw[d * 4 + 1];
        float w2 = cw[d * 4 + 2], w3 = cw[d * 4 + 3];
        float v = cb[d] + w3 * x0[i] + w2 * x1[i] + w1 * x2[i] + w0 * x3[i];
        r[i] = v / (1.f + __expf(-v));
    }
    *(f32x4*)&xc[(size_t)l * D_INNER + d4] = r;
    if (l == L_SEQ - 1) {
#pragma unroll
        for (int i = 0; i < 4; ++i) {
            int d = d4 + i;
            conv_state[d * 4 + 3] = x0[i];
            conv_state[d * 4 + 2] = x1[i];
            conv_state[d * 4 + 1] = x2[i];
            conv_state[d * 4 + 0] = x3[i];
        }
    }
}

// ---------------------------------------------------------------------------
// Chunked scan, phase 1. Thread = d (lane-coalesced), block.y = chunk.
// All 16 n-states in registers: no shuffles, no divergence, B broadcast.
// ---------------------------------------------------------------------------
__global__ __launch_bounds__(256) void scan_phase1(
    const float* __restrict__ delta, const float* __restrict__ xc,
    const float* __restrict__ dbl, const float* __restrict__ A_log,
    float* __restrict__ U, float* __restrict__ Aprod)
{
    int d = blockIdx.x * 256 + threadIdx.x;       // [0, D_INNER)
    int c = blockIdx.y;
    float a[D_STATE], h[D_STATE], p[D_STATE];
#pragma unroll
    for (int n = 0; n < D_STATE; n += 4) {
        f32x4 av = *(const f32x4*)&A_log[d * D_STATE + n];
#pragma unroll
        for (int e = 0; e < 4; ++e) {
            a[n + e] = __expf(av[e]);
            h[n + e] = 0.f;
            p[n + e] = 1.f;
        }
    }
    int l0 = c * SCAN_CL;
    for (int i = 0; i < SCAN_CL; ++i) {
        int l = l0 + i;
        float dl = delta[(size_t)l * D_INNER + d];
        float xv = xc[(size_t)l * D_INNER + d];
        const float* Bp = dbl + l * 128 + DT_RANK;
        f32x4 B0 = *(const f32x4*)(Bp);
        f32x4 B1 = *(const f32x4*)(Bp + 4);
        f32x4 B2 = *(const f32x4*)(Bp + 8);
        f32x4 B3 = *(const f32x4*)(Bp + 12);
        float dx = dl * xv;
#pragma unroll
        for (int n = 0; n < D_STATE; ++n) {
            float Bv = (n < 4) ? B0[n] : (n < 8) ? B1[n - 4]
                     : (n < 12) ? B2[n - 8] : B3[n - 12];
            float dA = __expf(-dl * a[n]);
            h[n] = fmaf(dA, h[n], dx * Bv);
            p[n] *= dA;
        }
    }
    size_t base = (size_t)c * NCHAIN + (size_t)d * D_STATE;
#pragma unroll
    for (int n = 0; n < D_STATE; n += 4) {
        *(f32x4*)&U[base + n]     = f32x4{h[n], h[n+1], h[n+2], h[n+3]};
        *(f32x4*)&Aprod[base + n] = f32x4{p[n], p[n+1], p[n+2], p[n+3]};
    }
}

// ---------------------------------------------------------------------------
// Phase 2: per (d,n) serial combine over NC chunks; writes last_state.
// ---------------------------------------------------------------------------
__global__ __launch_bounds__(256) void scan_phase2(
    const float* __restrict__ U, const float* __restrict__ Aprod,
    float* __restrict__ Hin, float* __restrict__ last_state)
{
    int r = blockIdx.x * 256 + threadIdx.x;
    float hin = 0.f;
#pragma unroll
    for (int c = 0; c < SCAN_NC; ++c) {
        Hin[c * NCHAIN + r] = hin;
        hin = fmaf(Aprod[c * NCHAIN + r], hin, U[c * NCHAIN + r]);
    }
    last_state[r] = hin;
}

// ---------------------------------------------------------------------------
// Phase 3: seeded local scan, 16 states in registers; in-thread n-reduction;
// y = (sum_n h*C + D*xc) * silu(z), coalesced [L][D] write.
// ---------------------------------------------------------------------------
__global__ __launch_bounds__(256) void scan_phase3(
    const float* __restrict__ delta, const float* __restrict__ xc,
    const float* __restrict__ z, const float* __restrict__ dbl,
    const float* __restrict__ A_log, const float* __restrict__ Dp,
    const float* __restrict__ Hin, float* __restrict__ y)
{
    int d = blockIdx.x * 256 + threadIdx.x;
    int c = blockIdx.y;
    float a[D_STATE], h[D_STATE];
    size_t hbase = (size_t)c * NCHAIN + (size_t)d * D_STATE;
#pragma unroll
    for (int n = 0; n < D_STATE; n += 4) {
        f32x4 av = *(const f32x4*)&A_log[d * D_STATE + n];
        f32x4 hv = *(const f32x4*)&Hin[hbase + n];
#pragma unroll
        for (int e = 0; e < 4; ++e) {
            a[n + e] = __expf(av[e]);
            h[n + e] = hv[e];
        }
    }
    float Dv = Dp[d];
    int l0 = c * SCAN_CL;
    for (int i = 0; i < SCAN_CL; ++i) {
        int l = l0 + i;
        float dl = delta[(size_t)l * D_INNER + d];
        float xv = xc[(size_t)l * D_INNER + d];
        float zv = z[(size_t)l * D_INNER + d];
        const float* Bp = dbl + l * 128 + DT_RANK;
        f32x4 B0 = *(const f32x4*)(Bp);
        f32x4 B1 = *(const f32x4*)(Bp + 4);
        f32x4 B2 = *(const f32x4*)(Bp + 8);
        f32x4 B3 = *(const f32x4*)(Bp + 12);
        f32x4 C0 = *(const f32x4*)(Bp + 16);
        f32x4 C1 = *(const f32x4*)(Bp + 20);
        f32x4 C2 = *(const f32x4*)(Bp + 24);
        f32x4 C3 = *(const f32x4*)(Bp + 28);
        float dx = dl * xv;
        float yv = 0.f;
#pragma unroll
        for (int n = 0; n < D_STATE; ++n) {
            float Bv = (n < 4) ? B0[n] : (n < 8) ? B1[n - 4]
                     : (n < 12) ? B2[n - 8] : B3[n - 12];
            float Cv = (n < 4) ? C0[n] : (n < 8) ? C1[n - 4]
                     : (n < 12) ? C2[n - 8] : C3[n - 12];
            float dA = __expf(-dl * a[n]);
            h[n] = fmaf(dA, h[n], dx * Bv);
            yv = fmaf(h[n], Cv, yv);
        }
        float sz = zv / (1.f + __expf(-zv));
        y[(size_t)l * D_INNER + d] = (yv + Dv * xv) * sz;
    }
}

// ---------------------------------------------------------------------------
extern "C" void kernel_launch(void* const* d_in, const int* in_sizes, int n_in,
                              void* d_out, int out_size, void* d_ws, size_t ws_size,
                              hipStream_t stream)
{
    const float* hs    = (const float*)d_in[0];
    const float* Win   = (const float*)d_in[1];
    const float* cw    = (const float*)d_in[2];
    const float* cb    = (const float*)d_in[3];
    const float* Wx    = (const float*)d_in[4];
    const float* Wdt   = (const float*)d_in[5];
    const float* dtb   = (const float*)d_in[6];
    const float* Wout  = (const float*)d_in[7];
    const float* A_log = (const float*)d_in[8];
    const float* Dp    = (const float*)d_in[9];

    float* out        = (float*)d_out;
    float* conv_state = out + (size_t)L_SEQ * D_MODEL;
    float* last_state = conv_state + (size_t)D_INNER * 4;

    const size_t NEED = sizeof(float) * (size_t)SCRATCH_FLOATS;
    float* base;
    if (ws_size >= NEED) {
        base = (float*)d_ws;
    } else {
        void* sp = nullptr;
        hipGetSymbolAddress(&sp, HIP_SYMBOL(g_scratch));
        base = (float*)sp;
    }
    float* buf0 = base;                                // x -> delta -> K7 partials
    float* buf1 = buf0 + (size_t)L_SEQ * D_INNER;      // z
    float* buf2 = buf1 + (size_t)L_SEQ * D_INNER;      // xc [L][D]
    float* buf3 = buf2 + (size_t)L_SEQ * D_INNER;      // y  [L][D]
    float* dbl  = buf3 + (size_t)L_SEQ * D_INNER;      // [1024][128]
    float* Ubuf = dbl  + (size_t)L_SEQ * 128;          // [NC][NCHAIN]
    float* Abuf = Ubuf + (size_t)SCAN_NC * NCHAIN;
    float* Hbuf = Abuf + (size_t)SCAN_NC * NCHAIN;

    // K1: xz = hs @ Win^T -> x (buf0), z (buf1).
    // BK=64 (24 iters), BM128/BN64, SWZY=12, grid 768.  (r17 proven best)
    gemm_bt<128, 64, 64, 1, 1, 0, 12><<<dim3(768), 256, 0, stream>>>(
        hs, Win, buf0, buf1, nullptr, L_SEQ, 2 * D_INNER, D_MODEL, D_MODEL, D_MODEL, D_INNER);

    // K2: conv + silu -> xc (buf2); conv_state; zeroes dbl (before K3)
    conv_silu<<<dim3(L_SEQ * D_INNER / 4 / 256), 256, 0, stream>>>(
        buf0, cw, cb, buf2, conv_state, dbl);

    // K3: dbl = xc @ Wx^T -> [L][128] (hi/lo both sides, split-K 24, atomic
    // into L2-resident 0.5 MB dbl)
    gemm_bt<64, 128, 32, 2, 2, 2><<<dim3(16, 1, 24), 256, 0, stream>>>(
        buf2, Wx, dbl, nullptr, nullptr, L_SEQ, 128, D_INNER, D_INNER, D_INNER, 128);

    // K4: delta = softplus(dt @ Wdt^T + b) -> buf0. BK=96: single LDS tile.
    gemm_bt<64, 64, 96, 2, 2, 1><<<dim3(16, 48), 256, 0, stream>>>(
        dbl, Wdt, buf0, nullptr, dtb, L_SEQ, D_INNER, DT_RANK, 128, DT_RANK, D_INNER);

    // K5: chunked scan (3 phases) -> y (buf3), last_state
    scan_phase1<<<dim3(D_INNER / 256, SCAN_NC), 256, 0, stream>>>(
        buf0, buf2, dbl, A_log, Ubuf, Abuf);
    scan_phase2<<<dim3(NCHAIN / 256), 256, 0, stream>>>(
        Ubuf, Abuf, Hbuf, last_state);
    scan_phase3<<<dim3(D_INNER / 256, SCAN_NC), 256, 0, stream>>>(
        buf0, buf2, buf1, dbl, A_log, Dp, Hbuf, buf3);

    // K7: out = y @ Wout^T, split-K=2 -> slabs in buf0 (delta dead); reduce.
    // SWZY=3: x-grid 384 = 8 XCD * 3 N-chunks * 16 M-blocks; per-XCD Wout
    // chunk 2.36 MB -> L2-resident (r20-verified lever, math-identical).
    gemm_bt<64, 64, 64, 1, 1, 4, 3><<<dim3(384, 1, 2), 256, 0, stream>>>(
        buf3, Wout, buf0, nullptr, nullptr, L_SEQ, D_MODEL, D_INNER, D_INNER, D_INNER, D_MODEL);
    reduce2_f32<<<dim3(L_SEQ * D_MODEL / 4 / 256), 256, 0, stream>>>(
        buf0, out, L_SEQ * D_MODEL / 4);
}